// Round 1
// baseline (364.064 us; speedup 1.0000x reference)
//
#include <hip/hip_runtime.h>
#include <cstdint>

typedef unsigned short u16;
typedef __attribute__((ext_vector_type(8))) short short8;
typedef __attribute__((ext_vector_type(4))) float floatx4;

#define BT    8192
#define TSEQ  2048
#define NBAT  4
#define CMOD  512
#define NH    4
#define HD    128
#define DFF   2048
#define CQKV  1536

__device__ __forceinline__ u16 f2bf(float f) {
  union { float f; uint32_t u; } v; v.f = f;
  uint32_t r = v.u + 0x7FFFu + ((v.u >> 16) & 1u);
  return (u16)(r >> 16);
}

// ---------------- weight transpose + cast: W[K][N] f32 -> Wt[N][K] bf16 ----------------
__global__ __launch_bounds__(256) void transpose_cast(const float* __restrict__ W,
                                                      u16* __restrict__ Wt, int K, int N) {
  __shared__ float tile[32][33];
  int n0 = blockIdx.x * 32, k0 = blockIdx.y * 32;
  int tx = threadIdx.x & 31, ty = threadIdx.x >> 5;
  #pragma unroll
  for (int r = 0; r < 32; r += 8)
    tile[r + ty][tx] = W[(size_t)(k0 + r + ty) * N + n0 + tx];
  __syncthreads();
  #pragma unroll
  for (int r = 0; r < 32; r += 8)
    Wt[(size_t)(n0 + r + ty) * K + k0 + tx] = f2bf(tile[tx][r + ty]);
}

// ---------------- layernorm: fp32 in -> bf16 out, one wave per 512-row ----------------
__global__ __launch_bounds__(256) void ln_kernel(const float* __restrict__ x,
                                                 const float* __restrict__ g,
                                                 const float* __restrict__ b,
                                                 u16* __restrict__ out) {
  int row = blockIdx.x * 4 + (threadIdx.x >> 6);
  int lane = threadIdx.x & 63;
  const float4* xr = (const float4*)(x + (size_t)row * CMOD);
  float4 a = xr[lane], c = xr[lane + 64];
  float s = a.x + a.y + a.z + a.w + c.x + c.y + c.z + c.w;
  float q = a.x*a.x + a.y*a.y + a.z*a.z + a.w*a.w
          + c.x*c.x + c.y*c.y + c.z*c.z + c.w*c.w;
  #pragma unroll
  for (int o = 32; o; o >>= 1) { s += __shfl_xor(s, o); q += __shfl_xor(q, o); }
  float mu = s * (1.0f / CMOD);
  float rstd = rsqrtf(q * (1.0f / CMOD) - mu * mu + 1e-5f);
  const float4* gr = (const float4*)g;
  const float4* br = (const float4*)b;
  float4 g0 = gr[lane], g1 = gr[lane + 64], b0 = br[lane], b1 = br[lane + 64];
  u16* orow = out + (size_t)row * CMOD;
  int i0 = lane * 4, i1 = (lane + 64) * 4;
  orow[i0 + 0] = f2bf((a.x - mu) * rstd * g0.x + b0.x);
  orow[i0 + 1] = f2bf((a.y - mu) * rstd * g0.y + b0.y);
  orow[i0 + 2] = f2bf((a.z - mu) * rstd * g0.z + b0.z);
  orow[i0 + 3] = f2bf((a.w - mu) * rstd * g0.w + b0.w);
  orow[i1 + 0] = f2bf((c.x - mu) * rstd * g1.x + b1.x);
  orow[i1 + 1] = f2bf((c.y - mu) * rstd * g1.y + b1.y);
  orow[i1 + 2] = f2bf((c.z - mu) * rstd * g1.z + b1.z);
  orow[i1 + 3] = f2bf((c.w - mu) * rstd * g1.w + b1.w);
}

// ---------------- MFMA GEMM: C[M][N] = A[M][K] * Bt[N][K]^T, 128x128 tile ----------------
// EPI 0: scatter q/k natural [bh][t][128] bf16, v transposed [bh][d][t] bf16
// EPI 1: outf = acc + resid (fp32), stride CMOD
// EPI 2: ob0 = bf16(gelu(acc)), stride DFF
// EPI 3: outf = acc + resid (fp32), stride CMOD
template <int EPI>
__global__ __launch_bounds__(256) void gemm_kernel(
    const u16* __restrict__ A, const u16* __restrict__ Bt, int K,
    const float* __restrict__ resid, float* __restrict__ outf,
    u16* __restrict__ ob0, u16* __restrict__ ob1, u16* __restrict__ ob2) {
  constexpr int LDT = 40;  // padded LDS stride (bf16 elems): 80B rows spread banks
  __shared__ __align__(16) u16 As[128 * LDT];
  __shared__ __align__(16) u16 Bs[128 * LDT];
  int tid = threadIdx.x;
  int lane = tid & 63, wave = tid >> 6;
  int lane16 = lane & 15, quad = lane >> 4;
  int m0 = blockIdx.y * 128, n0 = blockIdx.x * 128;
  int wm = (wave >> 1) * 64, wn = (wave & 1) * 64;
  int srow = tid >> 2, skc = (tid & 3) * 8;

  floatx4 acc[4][4];
  #pragma unroll
  for (int i = 0; i < 4; i++)
    #pragma unroll
    for (int j = 0; j < 4; j++) acc[i][j] = (floatx4)(0.0f);

  const u16* Arow0 = A + (size_t)(m0 + srow) * K + skc;
  const u16* Arow1 = A + (size_t)(m0 + srow + 64) * K + skc;
  const u16* Brow0 = Bt + (size_t)(n0 + srow) * K + skc;
  const u16* Brow1 = Bt + (size_t)(n0 + srow + 64) * K + skc;

  for (int k0 = 0; k0 < K; k0 += 32) {
    __syncthreads();
    *(short8*)&As[srow * LDT + skc]        = *(const short8*)(Arow0 + k0);
    *(short8*)&As[(srow + 64) * LDT + skc] = *(const short8*)(Arow1 + k0);
    *(short8*)&Bs[srow * LDT + skc]        = *(const short8*)(Brow0 + k0);
    *(short8*)&Bs[(srow + 64) * LDT + skc] = *(const short8*)(Brow1 + k0);
    __syncthreads();
    short8 af[4], bf[4];
    #pragma unroll
    for (int i = 0; i < 4; i++)
      af[i] = *(const short8*)&As[(wm + i * 16 + lane16) * LDT + quad * 8];
    #pragma unroll
    for (int j = 0; j < 4; j++)
      bf[j] = *(const short8*)&Bs[(wn + j * 16 + lane16) * LDT + quad * 8];
    #pragma unroll
    for (int i = 0; i < 4; i++)
      #pragma unroll
      for (int j = 0; j < 4; j++)
        acc[i][j] = __builtin_amdgcn_mfma_f32_16x16x32_bf16(af[i], bf[j], acc[i][j], 0, 0, 0);
  }

  #pragma unroll
  for (int i = 0; i < 4; i++) {
    #pragma unroll
    for (int j = 0; j < 4; j++) {
      #pragma unroll
      for (int r = 0; r < 4; r++) {
        int m = m0 + wm + i * 16 + quad * 4 + r;
        int n = n0 + wn + j * 16 + lane16;
        float v = acc[i][j][r];
        if (EPI == 0) {
          int bb = m >> 11, t = m & 2047;
          int nn = n & 511, which = n >> 9;
          int h = nn >> 7, d = nn & 127;
          size_t bh = (size_t)(bb * NH + h);
          if (which == 0)      ob0[bh * TSEQ * HD + (size_t)t * HD + d] = f2bf(v);
          else if (which == 1) ob1[bh * TSEQ * HD + (size_t)t * HD + d] = f2bf(v);
          else                 ob2[bh * HD * TSEQ + (size_t)d * TSEQ + t] = f2bf(v);
        } else if (EPI == 1) {
          size_t idx = (size_t)m * CMOD + n;
          outf[idx] = v + resid[idx];
        } else if (EPI == 2) {
          float ge = 0.5f * v * (1.0f + erff(v * 0.70710678118654752f));
          ob0[(size_t)m * DFF + n] = f2bf(ge);
        } else {
          size_t idx = (size_t)m * CMOD + n;
          outf[idx] = v + resid[idx];
        }
      }
    }
  }
}

// ---------------- flash attention: 1 block = 64 q rows, K-tile = 32 ----------------
__global__ __launch_bounds__(256) void attn_kernel(const u16* __restrict__ qb,
                                                   const u16* __restrict__ kb,
                                                   const u16* __restrict__ vtb,
                                                   u16* __restrict__ ob) {
  constexpr int KT = 136, VT = 40;  // padded strides
  __shared__ __align__(16) u16 Ks[32 * KT];   // [kpos][d]
  __shared__ __align__(16) u16 Vs[128 * VT];  // [d][kpos]  (from pre-transposed V)
  __shared__ __align__(16) u16 Ps[4 * 16 * VT];
  int tid = threadIdx.x, wave = tid >> 6, lane = tid & 63;
  int lane16 = lane & 15, quad = lane >> 4;
  int bh = blockIdx.x;
  int qt = 31 - (int)blockIdx.y;  // heavy (late) q-tiles dispatch first (LPT)
  int q0 = qt * 64;
  const u16* Q  = qb  + (size_t)bh * TSEQ * HD;
  const u16* Kg = kb  + (size_t)bh * TSEQ * HD;
  const u16* Vg = vtb + (size_t)bh * HD * TSEQ;

  short8 aq[4];
  int qrow = q0 + wave * 16 + lane16;
  #pragma unroll
  for (int cc = 0; cc < 4; cc++)
    aq[cc] = *(const short8*)&Q[(size_t)qrow * HD + cc * 32 + quad * 8];

  floatx4 o[8];
  #pragma unroll
  for (int j = 0; j < 8; j++) o[j] = (floatx4)(0.0f);
  float mrow[4] = {-1e30f, -1e30f, -1e30f, -1e30f};
  float lrow[4] = {0.0f, 0.0f, 0.0f, 0.0f};

  const float scale = 0.08838834764831845f;  // 1/sqrt(128)
  int ktiles = (q0 + 64) >> 5;
  int wqmax = q0 + wave * 16 + 15;
  int ksrow = tid >> 4, kscol = (tid & 15) * 8;
  int vsrow = tid >> 2, vscol = (tid & 3) * 8;
  u16* Pw = &Ps[wave * 16 * VT];

  for (int kt = 0; kt < ktiles; kt++) {
    __syncthreads();
    *(short8*)&Ks[ksrow * KT + kscol] =
        *(const short8*)&Kg[(size_t)(kt * 32 + ksrow) * HD + kscol];
    *(short8*)&Ks[(ksrow + 16) * KT + kscol] =
        *(const short8*)&Kg[(size_t)(kt * 32 + ksrow + 16) * HD + kscol];
    *(short8*)&Vs[vsrow * VT + vscol] =
        *(const short8*)&Vg[(size_t)vsrow * TSEQ + kt * 32 + vscol];
    *(short8*)&Vs[(vsrow + 64) * VT + vscol] =
        *(const short8*)&Vg[(size_t)(vsrow + 64) * TSEQ + kt * 32 + vscol];
    __syncthreads();
    if (kt * 32 > wqmax) continue;  // fully masked for this wave; barriers stay aligned

    floatx4 st0 = (floatx4)(0.0f), st1 = (floatx4)(0.0f);
    #pragma unroll
    for (int cc = 0; cc < 4; cc++) {
      short8 kf0 = *(const short8*)&Ks[lane16 * KT + cc * 32 + quad * 8];
      short8 kf1 = *(const short8*)&Ks[(16 + lane16) * KT + cc * 32 + quad * 8];
      st0 = __builtin_amdgcn_mfma_f32_16x16x32_bf16(aq[cc], kf0, st0, 0, 0, 0);
      st1 = __builtin_amdgcn_mfma_f32_16x16x32_bf16(aq[cc], kf1, st1, 0, 0, 0);
    }
    int qg = q0 + wave * 16 + quad * 4;
    int kg0 = kt * 32 + lane16, kg1 = kg0 + 16;
    #pragma unroll
    for (int r = 0; r < 4; r++) {
      float s0 = st0[r] * scale, s1 = st1[r] * scale;
      if (kg0 > qg + r) s0 = -1e30f;
      if (kg1 > qg + r) s1 = -1e30f;
      float mx = fmaxf(s0, s1);
      mx = fmaxf(mx, __shfl_xor(mx, 1));
      mx = fmaxf(mx, __shfl_xor(mx, 2));
      mx = fmaxf(mx, __shfl_xor(mx, 4));
      mx = fmaxf(mx, __shfl_xor(mx, 8));
      float mnew = fmaxf(mrow[r], mx);
      float alpha = __expf(mrow[r] - mnew);
      mrow[r] = mnew;
      float p0 = __expf(s0 - mnew);
      float p1 = __expf(s1 - mnew);
      float rs = p0 + p1;
      rs += __shfl_xor(rs, 1); rs += __shfl_xor(rs, 2);
      rs += __shfl_xor(rs, 4); rs += __shfl_xor(rs, 8);
      lrow[r] = lrow[r] * alpha + rs;
      #pragma unroll
      for (int j = 0; j < 8; j++) o[j][r] *= alpha;
      Pw[(quad * 4 + r) * VT + lane16]      = f2bf(p0);
      Pw[(quad * 4 + r) * VT + 16 + lane16] = f2bf(p1);
    }
    __builtin_amdgcn_s_waitcnt(0);  // drain this wave's P ds_writes before re-read
    short8 pf = *(const short8*)&Pw[lane16 * VT + quad * 8];
    #pragma unroll
    for (int j = 0; j < 8; j++) {
      short8 vf = *(const short8*)&Vs[(j * 16 + lane16) * VT + quad * 8];
      o[j] = __builtin_amdgcn_mfma_f32_16x16x32_bf16(pf, vf, o[j], 0, 0, 0);
    }
  }

  int bb = bh >> 2, h = bh & 3;
  #pragma unroll
  for (int j = 0; j < 8; j++)
    #pragma unroll
    for (int r = 0; r < 4; r++) {
      int t = q0 + wave * 16 + quad * 4 + r;
      float val = o[j][r] / lrow[r];
      ob[((size_t)(bb * TSEQ + t)) * CMOD + h * HD + j * 16 + lane16] = f2bf(val);
    }
}

extern "C" void kernel_launch(void* const* d_in, const int* in_sizes, int n_in,
                              void* d_out, int out_size, void* d_ws, size_t ws_size,
                              hipStream_t stream) {
  const float* x     = (const float*)d_in[0];
  const float* ln1g  = (const float*)d_in[1];
  const float* ln1b  = (const float*)d_in[2];
  const float* wqkv  = (const float*)d_in[3];
  const float* wproj = (const float*)d_in[4];
  const float* ln2g  = (const float*)d_in[5];
  const float* ln2b  = (const float*)d_in[6];
  const float* wff1  = (const float*)d_in[7];
  const float* wff2  = (const float*)d_in[8];
  float* out = (float*)d_out;
  char* ws = (char*)d_ws;

  u16* wt_qkv  = (u16*)(ws);             // 1536x512 bf16
  u16* wt_proj = (u16*)(ws + 1572864);   // 512x512
  u16* wt_ff1  = (u16*)(ws + 2097152);   // 2048x512
  u16* wt_ff2  = (u16*)(ws + 4194304);   // 512x2048
  u16* ln_buf  = (u16*)(ws + 6291456);   // 8192x512 bf16 (shared ln1/ln2 out)
  u16* q_buf   = (u16*)(ws + 14680064);  // [16][2048][128]
  u16* k_buf   = (u16*)(ws + 23068672);  // [16][2048][128]
  u16* vt_buf  = (u16*)(ws + 31457280);  // [16][128][2048]
  u16* attn    = (u16*)(ws + 39845888);  // 8192x512 bf16
  float* x2    = (float*)(ws + 48234496);// 8192x512 f32
  u16* h1      = (u16*)(ws + 65011712);  // 8192x2048 bf16

  dim3 blk(256);
  transpose_cast<<<dim3(CQKV / 32, CMOD / 32), blk, 0, stream>>>(wqkv, wt_qkv, CMOD, CQKV);
  transpose_cast<<<dim3(CMOD / 32, CMOD / 32), blk, 0, stream>>>(wproj, wt_proj, CMOD, CMOD);
  transpose_cast<<<dim3(DFF / 32, CMOD / 32), blk, 0, stream>>>(wff1, wt_ff1, CMOD, DFF);
  transpose_cast<<<dim3(CMOD / 32, DFF / 32), blk, 0, stream>>>(wff2, wt_ff2, DFF, CMOD);

  ln_kernel<<<dim3(BT / 4), blk, 0, stream>>>(x, ln1g, ln1b, ln_buf);

  gemm_kernel<0><<<dim3(CQKV / 128, BT / 128), blk, 0, stream>>>(
      ln_buf, wt_qkv, CMOD, nullptr, nullptr, q_buf, k_buf, vt_buf);

  attn_kernel<<<dim3(NBAT * NH, TSEQ / 64), blk, 0, stream>>>(q_buf, k_buf, vt_buf, attn);

  gemm_kernel<1><<<dim3(CMOD / 128, BT / 128), blk, 0, stream>>>(
      attn, wt_proj, CMOD, x, x2, nullptr, nullptr, nullptr);

  ln_kernel<<<dim3(BT / 4), blk, 0, stream>>>(x2, ln2g, ln2b, ln_buf);

  gemm_kernel<2><<<dim3(DFF / 128, BT / 128), blk, 0, stream>>>(
      ln_buf, wt_ff1, CMOD, nullptr, nullptr, h1, nullptr, nullptr);

  gemm_kernel<3><<<dim3(CMOD / 128, BT / 128), blk, 0, stream>>>(
      h1, wt_ff2, DFF, x2, out, nullptr, nullptr, nullptr);
}

// Round 2
// 295.409 us; speedup vs baseline: 1.2324x; 1.2324x over previous
//
#include <hip/hip_runtime.h>
#include <cstdint>

typedef unsigned short u16;
typedef __attribute__((ext_vector_type(8))) short short8;
typedef __attribute__((ext_vector_type(4))) float floatx4;

#define BT    8192
#define TSEQ  2048
#define NBAT  4
#define CMOD  512
#define NH    4
#define HD    128
#define DFF   2048
#define CQKV  1536

__device__ __forceinline__ u16 f2bf(float f) {
  union { float f; uint32_t u; } v; v.f = f;
  uint32_t r = v.u + 0x7FFFu + ((v.u >> 16) & 1u);
  return (u16)(r >> 16);
}

__device__ __forceinline__ float exp2a(float x) {
  float r; asm("v_exp_f32 %0, %1" : "=v"(r) : "v"(x)); return r;
}
__device__ __forceinline__ float rcpa(float x) {
  float r; asm("v_rcp_f32 %0, %1" : "=v"(r) : "v"(x)); return r;
}

typedef __attribute__((address_space(1))) const unsigned int ga_u32;
typedef __attribute__((address_space(3))) unsigned int ls_u32;
__device__ __forceinline__ void glds16(const u16* g, u16* l) {
  __builtin_amdgcn_global_load_lds((ga_u32*)g, (ls_u32*)l, 16, 0, 0);
}

// ---------------- weight transpose + cast: W[K][N] f32 -> Wt[N][K] bf16 ----------------
__global__ __launch_bounds__(256) void transpose_cast(const float* __restrict__ W,
                                                      u16* __restrict__ Wt, int K, int N) {
  __shared__ float tile[32][33];
  int n0 = blockIdx.x * 32, k0 = blockIdx.y * 32;
  int tx = threadIdx.x & 31, ty = threadIdx.x >> 5;
  #pragma unroll
  for (int r = 0; r < 32; r += 8)
    tile[r + ty][tx] = W[(size_t)(k0 + r + ty) * N + n0 + tx];
  __syncthreads();
  #pragma unroll
  for (int r = 0; r < 32; r += 8)
    Wt[(size_t)(n0 + r + ty) * K + k0 + tx] = f2bf(tile[tx][r + ty]);
}

// ---------------- layernorm: fp32 in -> bf16 out, one wave per 512-row ----------------
__global__ __launch_bounds__(256) void ln_kernel(const float* __restrict__ x,
                                                 const float* __restrict__ g,
                                                 const float* __restrict__ b,
                                                 u16* __restrict__ out) {
  int row = blockIdx.x * 4 + (threadIdx.x >> 6);
  int lane = threadIdx.x & 63;
  const float4* xr = (const float4*)(x + (size_t)row * CMOD);
  float4 a = xr[lane], c = xr[lane + 64];
  float s = a.x + a.y + a.z + a.w + c.x + c.y + c.z + c.w;
  float q = a.x*a.x + a.y*a.y + a.z*a.z + a.w*a.w
          + c.x*c.x + c.y*c.y + c.z*c.z + c.w*c.w;
  #pragma unroll
  for (int o = 32; o; o >>= 1) { s += __shfl_xor(s, o); q += __shfl_xor(q, o); }
  float mu = s * (1.0f / CMOD);
  float rstd = rsqrtf(q * (1.0f / CMOD) - mu * mu + 1e-5f);
  const float4* gr = (const float4*)g;
  const float4* br = (const float4*)b;
  float4 g0 = gr[lane], g1 = gr[lane + 64], b0 = br[lane], b1 = br[lane + 64];
  u16* orow = out + (size_t)row * CMOD;
  int i0 = lane * 4, i1 = (lane + 64) * 4;
  orow[i0 + 0] = f2bf((a.x - mu) * rstd * g0.x + b0.x);
  orow[i0 + 1] = f2bf((a.y - mu) * rstd * g0.y + b0.y);
  orow[i0 + 2] = f2bf((a.z - mu) * rstd * g0.z + b0.z);
  orow[i0 + 3] = f2bf((a.w - mu) * rstd * g0.w + b0.w);
  orow[i1 + 0] = f2bf((c.x - mu) * rstd * g1.x + b1.x);
  orow[i1 + 1] = f2bf((c.y - mu) * rstd * g1.y + b1.y);
  orow[i1 + 2] = f2bf((c.z - mu) * rstd * g1.z + b1.z);
  orow[i1 + 3] = f2bf((c.w - mu) * rstd * g1.w + b1.w);
}

// ---------------- MFMA GEMM: C[M][N] = A[M][K] * Bt[N][K]^T, 128x128 tile ----------------
// EPI 0: scatter q (pre-scaled by 1/sqrt(d)*log2e) / k natural [bh][t][128], v transposed [bh][d][t]
// EPI 1: outf = acc + resid (fp32), stride CMOD
// EPI 2: ob0 = bf16(gelu(acc)), stride DFF
// EPI 3: outf = acc + resid (fp32), stride CMOD
template <int EPI>
__global__ __launch_bounds__(256) void gemm_kernel(
    const u16* __restrict__ A, const u16* __restrict__ Bt, int K,
    const float* __restrict__ resid, float* __restrict__ outf,
    u16* __restrict__ ob0, u16* __restrict__ ob1, u16* __restrict__ ob2) {
  constexpr int LDT = 40;
  __shared__ __align__(16) u16 As[128 * LDT];
  __shared__ __align__(16) u16 Bs[128 * LDT];
  int tid = threadIdx.x;
  int lane = tid & 63, wave = tid >> 6;
  int lane16 = lane & 15, quad = lane >> 4;
  int m0 = blockIdx.y * 128, n0 = blockIdx.x * 128;
  int wm = (wave >> 1) * 64, wn = (wave & 1) * 64;
  int srow = tid >> 2, skc = (tid & 3) * 8;

  floatx4 acc[4][4];
  #pragma unroll
  for (int i = 0; i < 4; i++)
    #pragma unroll
    for (int j = 0; j < 4; j++) acc[i][j] = (floatx4)(0.0f);

  const u16* Arow0 = A + (size_t)(m0 + srow) * K + skc;
  const u16* Arow1 = A + (size_t)(m0 + srow + 64) * K + skc;
  const u16* Brow0 = Bt + (size_t)(n0 + srow) * K + skc;
  const u16* Brow1 = Bt + (size_t)(n0 + srow + 64) * K + skc;

  for (int k0 = 0; k0 < K; k0 += 32) {
    __syncthreads();
    *(short8*)&As[srow * LDT + skc]        = *(const short8*)(Arow0 + k0);
    *(short8*)&As[(srow + 64) * LDT + skc] = *(const short8*)(Arow1 + k0);
    *(short8*)&Bs[srow * LDT + skc]        = *(const short8*)(Brow0 + k0);
    *(short8*)&Bs[(srow + 64) * LDT + skc] = *(const short8*)(Brow1 + k0);
    __syncthreads();
    short8 af[4], bf[4];
    #pragma unroll
    for (int i = 0; i < 4; i++)
      af[i] = *(const short8*)&As[(wm + i * 16 + lane16) * LDT + quad * 8];
    #pragma unroll
    for (int j = 0; j < 4; j++)
      bf[j] = *(const short8*)&Bs[(wn + j * 16 + lane16) * LDT + quad * 8];
    #pragma unroll
    for (int i = 0; i < 4; i++)
      #pragma unroll
      for (int j = 0; j < 4; j++)
        acc[i][j] = __builtin_amdgcn_mfma_f32_16x16x32_bf16(af[i], bf[j], acc[i][j], 0, 0, 0);
  }

  #pragma unroll
  for (int i = 0; i < 4; i++) {
    #pragma unroll
    for (int j = 0; j < 4; j++) {
      #pragma unroll
      for (int r = 0; r < 4; r++) {
        int m = m0 + wm + i * 16 + quad * 4 + r;
        int n = n0 + wn + j * 16 + lane16;
        float v = acc[i][j][r];
        if (EPI == 0) {
          int bb = m >> 11, t = m & 2047;
          int nn = n & 511, which = n >> 9;
          int h = nn >> 7, d = nn & 127;
          size_t bh = (size_t)(bb * NH + h);
          // scale*log2e folded into Q so attention does p = exp2(s) directly
          if (which == 0)      ob0[bh * TSEQ * HD + (size_t)t * HD + d] = f2bf(v * 0.12751743f);
          else if (which == 1) ob1[bh * TSEQ * HD + (size_t)t * HD + d] = f2bf(v);
          else                 ob2[bh * HD * TSEQ + (size_t)d * TSEQ + t] = f2bf(v);
        } else if (EPI == 1) {
          size_t idx = (size_t)m * CMOD + n;
          outf[idx] = v + resid[idx];
        } else if (EPI == 2) {
          float ge = 0.5f * v * (1.0f + erff(v * 0.70710678118654752f));
          ob0[(size_t)m * DFF + n] = f2bf(ge);
        } else {
          size_t idx = (size_t)m * CMOD + n;
          outf[idx] = v + resid[idx];
        }
      }
    }
  }
}

// ---------------- flash attention v2 ----------------
// 4 waves/block, 16 q-rows per wave, K-tile = 32.
// - K/V staged via global_load_lds (16B) into XOR-swizzled LDS (conflict-free frags)
// - no-max softmax: p = exp2(s) (scale*log2e pre-folded into Q), row-sum l via ones-MFMA
// - P C->A layout fix via per-wave packed LDS round-trip (lgkmcnt-only wait)
__global__ __launch_bounds__(256) void attn_kernel(const u16* __restrict__ qb,
                                                   const u16* __restrict__ kb,
                                                   const u16* __restrict__ vtb,
                                                   u16* __restrict__ ob) {
  __shared__ __align__(16) u16 Ks[32 * 128];        // slot s=(r*16+c'), c' = c ^ (r&7)
  __shared__ __align__(16) u16 Vs[128 * 32];        // slot s=(d*4+c'),  c' = c ^ ((d>>1)&3)
  __shared__ __align__(16) uint32_t Ps[4 * 16 * 20];// per-wave P, row stride 20 dw (16B-aligned rows)
  int tid = threadIdx.x, wave = tid >> 6, lane = tid & 63;
  int lane16 = lane & 15, quad = lane >> 4;
  int bh = blockIdx.x;
  int qt = 31 - (int)blockIdx.y;  // LPT: heavy q-tiles first
  int q0w = qt * 64 + wave * 16;
  const u16* Q  = qb  + (size_t)bh * TSEQ * HD;
  const u16* Kg = kb  + (size_t)bh * TSEQ * HD;
  const u16* Vg = vtb + (size_t)bh * HD * TSEQ;

  short8 aq[4];
  {
    int qrow = q0w + lane16;
    #pragma unroll
    for (int cc = 0; cc < 4; cc++)
      aq[cc] = *(const short8*)&Q[(size_t)qrow * HD + cc * 32 + quad * 8];
  }

  // staging pointers: lane's global source for its fixed LDS slot (swizzle on source side)
  const u16* kgp[2]; const u16* vgp[2]; u16* klp[2]; u16* vlp[2];
  #pragma unroll
  for (int i = 0; i < 2; i++) {
    int s = wave * 128 + i * 64 + lane;
    int r = s >> 4, cp = s & 15, c = cp ^ (r & 7);
    kgp[i] = Kg + (size_t)r * HD + c * 8;
    klp[i] = Ks + (size_t)(wave * 128 + i * 64) * 8;
    int d = s >> 2, cv = (s & 3) ^ ((d >> 1) & 3);
    vgp[i] = Vg + (size_t)d * TSEQ + cv * 8;
    vlp[i] = Vs + (size_t)(wave * 128 + i * 64) * 8;
  }

  int ktw = (q0w >> 5) + 1;                 // this wave's causal tile count
  int ktblk = ((qt * 64 + 48) >> 5) + 1;    // block staging tile count (max over waves)

  floatx4 o[8];
  #pragma unroll
  for (int j = 0; j < 8; j++) o[j] = (floatx4)(0.0f);
  floatx4 ol = (floatx4)(0.0f);

  short8 ones;
  #pragma unroll
  for (int e = 0; e < 8; e++) ones[e] = (short)0x3F80;  // bf16 1.0

  uint32_t* Pw = &Ps[wave * 320];
  int swl = lane16 & 7;
  int cvr = quad ^ ((lane16 >> 1) & 3);

  for (int kt = 0; kt < ktblk; kt++) {
    __syncthreads();
    glds16(kgp[0] + (size_t)kt * 32 * HD, klp[0]);
    glds16(kgp[1] + (size_t)kt * 32 * HD, klp[1]);
    glds16(vgp[0] + kt * 32, vlp[0]);
    glds16(vgp[1] + kt * 32, vlp[1]);
    __syncthreads();
    if (kt >= ktw) continue;  // wave-uniform; barriers stay aligned

    // QK^T (Q pre-scaled): S row=quad*4+r (q), col=lane16 (kpos)
    floatx4 st0 = (floatx4)(0.0f), st1 = (floatx4)(0.0f);
    #pragma unroll
    for (int cc = 0; cc < 4; cc++) {
      short8 kf0 = *(const short8*)&Ks[(lane16 * 16 + ((cc * 4 + quad) ^ swl)) * 8];
      short8 kf1 = *(const short8*)&Ks[((16 + lane16) * 16 + ((cc * 4 + quad) ^ swl)) * 8];
      st0 = __builtin_amdgcn_mfma_f32_16x16x32_bf16(aq[cc], kf0, st0, 0, 0, 0);
      st1 = __builtin_amdgcn_mfma_f32_16x16x32_bf16(aq[cc], kf1, st1, 0, 0, 0);
    }
    // V B-frags (hoisted before P round-trip)
    short8 vf[8];
    #pragma unroll
    for (int j = 0; j < 8; j++)
      vf[j] = *(const short8*)&Vs[((j * 16 + lane16) * 4 + cvr) * 8];

    // p = exp2(s), causal mask, pack pairs (kpos c, c+16) into dword col c
    int kg0 = kt * 32 + lane16;
    #pragma unroll
    for (int r = 0; r < 4; r++) {
      int qr = q0w + quad * 4 + r;
      float p0 = exp2a(st0[r]);
      float p1 = exp2a(st1[r]);
      if (kg0 > qr) p0 = 0.0f;
      if (kg0 + 16 > qr) p1 = 0.0f;
      Pw[(quad * 4 + r) * 20 + lane16] =
          __builtin_amdgcn_perm(__float_as_uint(p1), __float_as_uint(p0), 0x07060302u);
    }
    asm volatile("s_waitcnt lgkmcnt(0)" ::: "memory");

    // A-frag read: row lane16, dword cols (quad&1)*8 + t, halves quad>>1
    union { uint32_t u[4]; short8 s; } pf;
    {
      const uint32_t* prow = &Pw[lane16 * 20 + (quad & 1) * 8];
      uint32_t d0 = prow[0], d1 = prow[1], d2 = prow[2], d3 = prow[3];
      uint32_t d4 = prow[4], d5 = prow[5], d6 = prow[6], d7 = prow[7];
      uint32_t sel = (quad >> 1) ? 0x07060302u : 0x05040100u;
      pf.u[0] = __builtin_amdgcn_perm(d1, d0, sel);
      pf.u[1] = __builtin_amdgcn_perm(d3, d2, sel);
      pf.u[2] = __builtin_amdgcn_perm(d5, d4, sel);
      pf.u[3] = __builtin_amdgcn_perm(d7, d6, sel);
    }
    #pragma unroll
    for (int j = 0; j < 8; j++)
      o[j] = __builtin_amdgcn_mfma_f32_16x16x32_bf16(pf.s, vf[j], o[j], 0, 0, 0);
    ol = __builtin_amdgcn_mfma_f32_16x16x32_bf16(pf.s, ones, ol, 0, 0, 0);
  }

  int bb = bh >> 2, h = bh & 3;
  #pragma unroll
  for (int r = 0; r < 4; r++) {
    int t = q0w + quad * 4 + r;
    float inv = rcpa(ol[r]);
    #pragma unroll
    for (int j = 0; j < 8; j++)
      ob[((size_t)(bb * TSEQ + t)) * CMOD + h * HD + j * 16 + lane16] = f2bf(o[j][r] * inv);
  }
}

extern "C" void kernel_launch(void* const* d_in, const int* in_sizes, int n_in,
                              void* d_out, int out_size, void* d_ws, size_t ws_size,
                              hipStream_t stream) {
  const float* x     = (const float*)d_in[0];
  const float* ln1g  = (const float*)d_in[1];
  const float* ln1b  = (const float*)d_in[2];
  const float* wqkv  = (const float*)d_in[3];
  const float* wproj = (const float*)d_in[4];
  const float* ln2g  = (const float*)d_in[5];
  const float* ln2b  = (const float*)d_in[6];
  const float* wff1  = (const float*)d_in[7];
  const float* wff2  = (const float*)d_in[8];
  float* out = (float*)d_out;
  char* ws = (char*)d_ws;

  u16* wt_qkv  = (u16*)(ws);
  u16* wt_proj = (u16*)(ws + 1572864);
  u16* wt_ff1  = (u16*)(ws + 2097152);
  u16* wt_ff2  = (u16*)(ws + 4194304);
  u16* ln_buf  = (u16*)(ws + 6291456);
  u16* q_buf   = (u16*)(ws + 14680064);
  u16* k_buf   = (u16*)(ws + 23068672);
  u16* vt_buf  = (u16*)(ws + 31457280);
  u16* attn    = (u16*)(ws + 39845888);
  float* x2    = (float*)(ws + 48234496);
  u16* h1      = (u16*)(ws + 65011712);

  dim3 blk(256);
  transpose_cast<<<dim3(CQKV / 32, CMOD / 32), blk, 0, stream>>>(wqkv, wt_qkv, CMOD, CQKV);
  transpose_cast<<<dim3(CMOD / 32, CMOD / 32), blk, 0, stream>>>(wproj, wt_proj, CMOD, CMOD);
  transpose_cast<<<dim3(DFF / 32, CMOD / 32), blk, 0, stream>>>(wff1, wt_ff1, CMOD, DFF);
  transpose_cast<<<dim3(CMOD / 32, DFF / 32), blk, 0, stream>>>(wff2, wt_ff2, DFF, CMOD);

  ln_kernel<<<dim3(BT / 4), blk, 0, stream>>>(x, ln1g, ln1b, ln_buf);

  gemm_kernel<0><<<dim3(CQKV / 128, BT / 128), blk, 0, stream>>>(
      ln_buf, wt_qkv, CMOD, nullptr, nullptr, q_buf, k_buf, vt_buf);

  attn_kernel<<<dim3(NBAT * NH, TSEQ / 64), blk, 0, stream>>>(q_buf, k_buf, vt_buf, attn);

  gemm_kernel<1><<<dim3(CMOD / 128, BT / 128), blk, 0, stream>>>(
      attn, wt_proj, CMOD, x, x2, nullptr, nullptr, nullptr);

  ln_kernel<<<dim3(BT / 4), blk, 0, stream>>>(x2, ln2g, ln2b, ln_buf);

  gemm_kernel<2><<<dim3(DFF / 128, BT / 128), blk, 0, stream>>>(
      ln_buf, wt_ff1, CMOD, nullptr, nullptr, h1, nullptr, nullptr);

  gemm_kernel<3><<<dim3(CMOD / 128, BT / 128), blk, 0, stream>>>(
      h1, wt_ff2, DFF, x2, out, nullptr, nullptr, nullptr);
}

// Round 3
// 285.271 us; speedup vs baseline: 1.2762x; 1.0355x over previous
//
#include <hip/hip_runtime.h>
#include <cstdint>

typedef unsigned short u16;
typedef __attribute__((ext_vector_type(8))) short short8;
typedef __attribute__((ext_vector_type(4))) float floatx4;

#define BT    8192
#define TSEQ  2048
#define NBAT  4
#define CMOD  512
#define NH    4
#define HD    128
#define DFF   2048
#define CQKV  1536

__device__ __forceinline__ u16 f2bf(float f) {
  union { float f; uint32_t u; } v; v.f = f;
  uint32_t r = v.u + 0x7FFFu + ((v.u >> 16) & 1u);
  return (u16)(r >> 16);
}

__device__ __forceinline__ float exp2a(float x) {
  float r; asm("v_exp_f32 %0, %1" : "=v"(r) : "v"(x)); return r;
}
__device__ __forceinline__ float rcpa(float x) {
  float r; asm("v_rcp_f32 %0, %1" : "=v"(r) : "v"(x)); return r;
}

typedef __attribute__((address_space(1))) const unsigned int ga_u32;
typedef __attribute__((address_space(3))) unsigned int ls_u32;
__device__ __forceinline__ void glds16(const u16* g, u16* l) {
  __builtin_amdgcn_global_load_lds((ga_u32*)g, (ls_u32*)l, 16, 0, 0);
}

// ---------------- weight transpose + cast: W[K][N] f32 -> Wt[N][K] bf16 ----------------
__global__ __launch_bounds__(256) void transpose_cast(const float* __restrict__ W,
                                                      u16* __restrict__ Wt, int K, int N) {
  __shared__ float tile[32][33];
  int n0 = blockIdx.x * 32, k0 = blockIdx.y * 32;
  int tx = threadIdx.x & 31, ty = threadIdx.x >> 5;
  #pragma unroll
  for (int r = 0; r < 32; r += 8)
    tile[r + ty][tx] = W[(size_t)(k0 + r + ty) * N + n0 + tx];
  __syncthreads();
  #pragma unroll
  for (int r = 0; r < 32; r += 8)
    Wt[(size_t)(n0 + r + ty) * K + k0 + tx] = f2bf(tile[tx][r + ty]);
}

// ---------------- layernorm: fp32 in -> bf16 out, one wave per 512-row ----------------
__global__ __launch_bounds__(256) void ln_kernel(const float* __restrict__ x,
                                                 const float* __restrict__ g,
                                                 const float* __restrict__ b,
                                                 u16* __restrict__ out) {
  int row = blockIdx.x * 4 + (threadIdx.x >> 6);
  int lane = threadIdx.x & 63;
  const float4* xr = (const float4*)(x + (size_t)row * CMOD);
  float4 a = xr[lane], c = xr[lane + 64];
  float s = a.x + a.y + a.z + a.w + c.x + c.y + c.z + c.w;
  float q = a.x*a.x + a.y*a.y + a.z*a.z + a.w*a.w
          + c.x*c.x + c.y*c.y + c.z*c.z + c.w*c.w;
  #pragma unroll
  for (int o = 32; o; o >>= 1) { s += __shfl_xor(s, o); q += __shfl_xor(q, o); }
  float mu = s * (1.0f / CMOD);
  float rstd = rsqrtf(q * (1.0f / CMOD) - mu * mu + 1e-5f);
  const float4* gr = (const float4*)g;
  const float4* br = (const float4*)b;
  float4 g0 = gr[lane], g1 = gr[lane + 64], b0 = br[lane], b1 = br[lane + 64];
  u16* orow = out + (size_t)row * CMOD;
  int i0 = lane * 4, i1 = (lane + 64) * 4;
  orow[i0 + 0] = f2bf((a.x - mu) * rstd * g0.x + b0.x);
  orow[i0 + 1] = f2bf((a.y - mu) * rstd * g0.y + b0.y);
  orow[i0 + 2] = f2bf((a.z - mu) * rstd * g0.z + b0.z);
  orow[i0 + 3] = f2bf((a.w - mu) * rstd * g0.w + b0.w);
  orow[i1 + 0] = f2bf((c.x - mu) * rstd * g1.x + b1.x);
  orow[i1 + 1] = f2bf((c.y - mu) * rstd * g1.y + b1.y);
  orow[i1 + 2] = f2bf((c.z - mu) * rstd * g1.z + b1.z);
  orow[i1 + 3] = f2bf((c.w - mu) * rstd * g1.w + b1.w);
}

// ---------------- MFMA GEMM: C[M][N] = A[M][K] * Bt[N][K]^T ----------------
// TM=128 fixed; TN = 128 or 64. glds16 staging, double-buffered LDS prefetch.
// EPI 0: scatter q (pre-scaled by 1/sqrt(d)*log2e) / k natural, v transposed
// EPI 1/3: outf = acc + resid (fp32). EPI 2: ob0 = bf16(gelu(acc)).
template <int EPI, int TN>
__global__ __launch_bounds__(256) void gemm_kernel(
    const u16* __restrict__ A, const u16* __restrict__ Bt, int K,
    const float* __restrict__ resid, float* __restrict__ outf,
    u16* __restrict__ ob0, u16* __restrict__ ob1, u16* __restrict__ ob2) {
  constexpr int WNF = TN / 32;   // n-frags per wave
  constexpr int NKB = TN / 64;   // B staging rounds
  __shared__ __align__(16) u16 As[2][128 * 32];
  __shared__ __align__(16) u16 Bs[2][TN * 32];
  int tid = threadIdx.x;
  int lane = tid & 63, wave = tid >> 6;
  int lane16 = lane & 15, quad = lane >> 4;
  int m0 = blockIdx.y * 128, n0 = blockIdx.x * TN;
  int wm = (wave >> 1) * 64, wn = (wave & 1) * (TN / 2);

  floatx4 acc[4][WNF];
  #pragma unroll
  for (int i = 0; i < 4; i++)
    #pragma unroll
    for (int j = 0; j < WNF; j++) acc[i][j] = (floatx4)(0.0f);

  // per-lane global source pointers (k0 added per tile), wave-uniform LDS bases
  const u16* agp[2]; u16* alp[2][2];
  const u16* bgp[NKB]; u16* blp[NKB][2];
  #pragma unroll
  for (int i = 0; i < 2; i++) {
    int s = i * 256 + tid;
    agp[i] = A + (size_t)(m0 + (s >> 2)) * K + (s & 3) * 8;
    alp[i][0] = &As[0][(i * 256 + wave * 64) * 8];
    alp[i][1] = &As[1][(i * 256 + wave * 64) * 8];
  }
  #pragma unroll
  for (int i = 0; i < NKB; i++) {
    int s = i * 256 + tid;
    bgp[i] = Bt + (size_t)(n0 + (s >> 2)) * K + (s & 3) * 8;
    blp[i][0] = &Bs[0][(i * 256 + wave * 64) * 8];
    blp[i][1] = &Bs[1][(i * 256 + wave * 64) * 8];
  }

  int nk = K >> 5;
  // prologue: stage tile 0 into buffer 0
  #pragma unroll
  for (int i = 0; i < 2; i++) glds16(agp[i], alp[i][0]);
  #pragma unroll
  for (int i = 0; i < NKB; i++) glds16(bgp[i], blp[i][0]);

  for (int kt = 0; kt < nk; kt++) {
    __syncthreads();  // drains loads for buf (kt&1), publishes to all waves
    int buf = kt & 1;
    if (kt + 1 < nk) {  // prefetch next tile into other buffer
      int k1 = (kt + 1) * 32;
      #pragma unroll
      for (int i = 0; i < 2; i++) glds16(agp[i] + k1, alp[i][buf ^ 1]);
      #pragma unroll
      for (int i = 0; i < NKB; i++) glds16(bgp[i] + k1, blp[i][buf ^ 1]);
    }
    short8 af[4], bf[WNF];
    #pragma unroll
    for (int i = 0; i < 4; i++)
      af[i] = *(const short8*)&As[buf][(wm + i * 16 + lane16) * 32 + quad * 8];
    #pragma unroll
    for (int j = 0; j < WNF; j++)
      bf[j] = *(const short8*)&Bs[buf][(wn + j * 16 + lane16) * 32 + quad * 8];
    #pragma unroll
    for (int i = 0; i < 4; i++)
      #pragma unroll
      for (int j = 0; j < WNF; j++)
        acc[i][j] = __builtin_amdgcn_mfma_f32_16x16x32_bf16(af[i], bf[j], acc[i][j], 0, 0, 0);
  }

  #pragma unroll
  for (int i = 0; i < 4; i++) {
    #pragma unroll
    for (int j = 0; j < WNF; j++) {
      #pragma unroll
      for (int r = 0; r < 4; r++) {
        int m = m0 + wm + i * 16 + quad * 4 + r;
        int n = n0 + wn + j * 16 + lane16;
        float v = acc[i][j][r];
        if (EPI == 0) {
          int bb = m >> 11, t = m & 2047;
          int nn = n & 511, which = n >> 9;
          int h = nn >> 7, d = nn & 127;
          size_t bh = (size_t)(bb * NH + h);
          if (which == 0)      ob0[bh * TSEQ * HD + (size_t)t * HD + d] = f2bf(v * 0.12751743f);
          else if (which == 1) ob1[bh * TSEQ * HD + (size_t)t * HD + d] = f2bf(v);
          else                 ob2[bh * HD * TSEQ + (size_t)d * TSEQ + t] = f2bf(v);
        } else if (EPI == 1) {
          size_t idx = (size_t)m * CMOD + n;
          outf[idx] = v + resid[idx];
        } else if (EPI == 2) {
          float ge = 0.5f * v * (1.0f + erff(v * 0.70710678118654752f));
          ob0[(size_t)m * DFF + n] = f2bf(ge);
        } else {
          size_t idx = (size_t)m * CMOD + n;
          outf[idx] = v + resid[idx];
        }
      }
    }
  }
}

// ---------------- flash attention v3: double-buffered K/V prefetch ----------------
__global__ __launch_bounds__(256) void attn_kernel(const u16* __restrict__ qb,
                                                   const u16* __restrict__ kb,
                                                   const u16* __restrict__ vtb,
                                                   u16* __restrict__ ob) {
  __shared__ __align__(16) u16 Ks[2][32 * 128];      // slot s=(r*16+c'), c' = c ^ (r&7)
  __shared__ __align__(16) u16 Vs[2][128 * 32];      // slot s=(d*4+c'),  c' = c ^ ((d>>1)&3)
  __shared__ __align__(16) uint32_t Ps[4 * 16 * 20]; // per-wave P rows, stride 20 dw
  int tid = threadIdx.x, wave = tid >> 6, lane = tid & 63;
  int lane16 = lane & 15, quad = lane >> 4;
  int bh = blockIdx.x;
  int qt = 31 - (int)blockIdx.y;  // LPT: heavy q-tiles first
  int q0w = qt * 64 + wave * 16;
  const u16* Q  = qb  + (size_t)bh * TSEQ * HD;
  const u16* Kg = kb  + (size_t)bh * TSEQ * HD;
  const u16* Vg = vtb + (size_t)bh * HD * TSEQ;

  short8 aq[4];
  {
    int qrow = q0w + lane16;
    #pragma unroll
    for (int cc = 0; cc < 4; cc++)
      aq[cc] = *(const short8*)&Q[(size_t)qrow * HD + cc * 32 + quad * 8];
  }

  // staging pointers (source-side swizzle; LDS dest lane-contiguous)
  const u16* kgp[2]; const u16* vgp[2];
  u16* klp[2][2]; u16* vlp[2][2];
  #pragma unroll
  for (int i = 0; i < 2; i++) {
    int s = wave * 128 + i * 64 + lane;
    int r = s >> 4, cp = s & 15, c = cp ^ (r & 7);
    kgp[i] = Kg + (size_t)r * HD + c * 8;
    int d = s >> 2, cv = (s & 3) ^ ((d >> 1) & 3);
    vgp[i] = Vg + (size_t)d * TSEQ + cv * 8;
    #pragma unroll
    for (int bfr = 0; bfr < 2; bfr++) {
      klp[i][bfr] = &Ks[bfr][(wave * 128 + i * 64) * 8];
      vlp[i][bfr] = &Vs[bfr][(wave * 128 + i * 64) * 8];
    }
  }

  int ktw = (q0w >> 5) + 1;               // this wave's causal tile count
  int ktblk = qt * 2 + 2;                 // block staging tile count

  floatx4 o[8];
  #pragma unroll
  for (int j = 0; j < 8; j++) o[j] = (floatx4)(0.0f);
  floatx4 ol = (floatx4)(0.0f);

  short8 ones;
  #pragma unroll
  for (int e = 0; e < 8; e++) ones[e] = (short)0x3F80;  // bf16 1.0

  uint32_t* Pw = &Ps[wave * 320];
  int swl = lane16 & 7;
  int cvr = quad ^ ((lane16 >> 1) & 3);

  // prologue: stage tile 0 into buffer 0
  #pragma unroll
  for (int i = 0; i < 2; i++) { glds16(kgp[i], klp[i][0]); glds16(vgp[i], vlp[i][0]); }

  for (int kt = 0; kt < ktblk; kt++) {
    __syncthreads();  // drains buf (kt&1) loads
    int buf = kt & 1;
    if (kt + 1 < ktblk) {
      int ko = (kt + 1) * 32;
      #pragma unroll
      for (int i = 0; i < 2; i++) {
        glds16(kgp[i] + (size_t)ko * HD, klp[i][buf ^ 1]);
        glds16(vgp[i] + ko, vlp[i][buf ^ 1]);
      }
    }
    if (kt >= ktw) continue;  // wave-uniform; barrier count stays aligned

    // QK^T (Q pre-scaled): S row=quad*4+r (q), col=lane16 (kpos)
    floatx4 st0 = (floatx4)(0.0f), st1 = (floatx4)(0.0f);
    #pragma unroll
    for (int cc = 0; cc < 4; cc++) {
      short8 kf0 = *(const short8*)&Ks[buf][(lane16 * 16 + ((cc * 4 + quad) ^ swl)) * 8];
      short8 kf1 = *(const short8*)&Ks[buf][((16 + lane16) * 16 + ((cc * 4 + quad) ^ swl)) * 8];
      st0 = __builtin_amdgcn_mfma_f32_16x16x32_bf16(aq[cc], kf0, st0, 0, 0, 0);
      st1 = __builtin_amdgcn_mfma_f32_16x16x32_bf16(aq[cc], kf1, st1, 0, 0, 0);
    }
    // V B-frags (hoisted before P round-trip)
    short8 vf[8];
    #pragma unroll
    for (int j = 0; j < 8; j++)
      vf[j] = *(const short8*)&Vs[buf][((j * 16 + lane16) * 4 + cvr) * 8];

    // p = exp2(s), causal mask, pack (kpos c, c+16) into dword col c
    int kg0 = kt * 32 + lane16;
    #pragma unroll
    for (int r = 0; r < 4; r++) {
      int qr = q0w + quad * 4 + r;
      float p0 = exp2a(st0[r]);
      float p1 = exp2a(st1[r]);
      if (kg0 > qr) p0 = 0.0f;
      if (kg0 + 16 > qr) p1 = 0.0f;
      Pw[(quad * 4 + r) * 20 + lane16] =
          __builtin_amdgcn_perm(__float_as_uint(p1), __float_as_uint(p0), 0x07060302u);
    }
    asm volatile("s_waitcnt lgkmcnt(0)" ::: "memory");

    union { uint32_t u[4]; short8 s; } pf;
    {
      const uint32_t* prow = &Pw[lane16 * 20 + (quad & 1) * 8];
      uint32_t d0 = prow[0], d1 = prow[1], d2 = prow[2], d3 = prow[3];
      uint32_t d4 = prow[4], d5 = prow[5], d6 = prow[6], d7 = prow[7];
      uint32_t sel = (quad >> 1) ? 0x07060302u : 0x05040100u;
      pf.u[0] = __builtin_amdgcn_perm(d1, d0, sel);
      pf.u[1] = __builtin_amdgcn_perm(d3, d2, sel);
      pf.u[2] = __builtin_amdgcn_perm(d5, d4, sel);
      pf.u[3] = __builtin_amdgcn_perm(d7, d6, sel);
    }
    #pragma unroll
    for (int j = 0; j < 8; j++)
      o[j] = __builtin_amdgcn_mfma_f32_16x16x32_bf16(pf.s, vf[j], o[j], 0, 0, 0);
    ol = __builtin_amdgcn_mfma_f32_16x16x32_bf16(pf.s, ones, ol, 0, 0, 0);
  }

  int bb = bh >> 2, h = bh & 3;
  #pragma unroll
  for (int r = 0; r < 4; r++) {
    int t = q0w + quad * 4 + r;
    float inv = rcpa(ol[r]);
    #pragma unroll
    for (int j = 0; j < 8; j++)
      ob[((size_t)(bb * TSEQ + t)) * CMOD + h * HD + j * 16 + lane16] = f2bf(o[j][r] * inv);
  }
}

extern "C" void kernel_launch(void* const* d_in, const int* in_sizes, int n_in,
                              void* d_out, int out_size, void* d_ws, size_t ws_size,
                              hipStream_t stream) {
  const float* x     = (const float*)d_in[0];
  const float* ln1g  = (const float*)d_in[1];
  const float* ln1b  = (const float*)d_in[2];
  const float* wqkv  = (const float*)d_in[3];
  const float* wproj = (const float*)d_in[4];
  const float* ln2g  = (const float*)d_in[5];
  const float* ln2b  = (const float*)d_in[6];
  const float* wff1  = (const float*)d_in[7];
  const float* wff2  = (const float*)d_in[8];
  float* out = (float*)d_out;
  char* ws = (char*)d_ws;

  u16* wt_qkv  = (u16*)(ws);
  u16* wt_proj = (u16*)(ws + 1572864);
  u16* wt_ff1  = (u16*)(ws + 2097152);
  u16* wt_ff2  = (u16*)(ws + 4194304);
  u16* ln_buf  = (u16*)(ws + 6291456);
  u16* q_buf   = (u16*)(ws + 14680064);
  u16* k_buf   = (u16*)(ws + 23068672);
  u16* vt_buf  = (u16*)(ws + 31457280);
  u16* attn    = (u16*)(ws + 39845888);
  float* x2    = (float*)(ws + 48234496);
  u16* h1      = (u16*)(ws + 65011712);

  dim3 blk(256);
  transpose_cast<<<dim3(CQKV / 32, CMOD / 32), blk, 0, stream>>>(wqkv, wt_qkv, CMOD, CQKV);
  transpose_cast<<<dim3(CMOD / 32, CMOD / 32), blk, 0, stream>>>(wproj, wt_proj, CMOD, CMOD);
  transpose_cast<<<dim3(DFF / 32, CMOD / 32), blk, 0, stream>>>(wff1, wt_ff1, CMOD, DFF);
  transpose_cast<<<dim3(CMOD / 32, DFF / 32), blk, 0, stream>>>(wff2, wt_ff2, DFF, CMOD);

  ln_kernel<<<dim3(BT / 4), blk, 0, stream>>>(x, ln1g, ln1b, ln_buf);

  gemm_kernel<0, 128><<<dim3(CQKV / 128, BT / 128), blk, 0, stream>>>(
      ln_buf, wt_qkv, CMOD, nullptr, nullptr, q_buf, k_buf, vt_buf);

  attn_kernel<<<dim3(NBAT * NH, TSEQ / 64), blk, 0, stream>>>(q_buf, k_buf, vt_buf, attn);

  gemm_kernel<1, 64><<<dim3(CMOD / 64, BT / 128), blk, 0, stream>>>(
      attn, wt_proj, CMOD, x, x2, nullptr, nullptr, nullptr);

  ln_kernel<<<dim3(BT / 4), blk, 0, stream>>>(x2, ln2g, ln2b, ln_buf);

  gemm_kernel<2, 128><<<dim3(DFF / 128, BT / 128), blk, 0, stream>>>(
      ln_buf, wt_ff1, CMOD, nullptr, nullptr, h1, nullptr, nullptr);

  gemm_kernel<3, 64><<<dim3(CMOD / 64, BT / 128), blk, 0, stream>>>(
      h1, wt_ff2, DFF, x2, out, nullptr, nullptr, nullptr);
}

// Round 4
// 276.692 us; speedup vs baseline: 1.3158x; 1.0310x over previous
//
#include <hip/hip_runtime.h>
#include <cstdint>

typedef unsigned short u16;
typedef __attribute__((ext_vector_type(8))) short short8;
typedef __attribute__((ext_vector_type(4))) float floatx4;

#define BT    8192
#define TSEQ  2048
#define NBAT  4
#define CMOD  512
#define NH    4
#define HD    128
#define DFF   2048
#define CQKV  1536

__device__ __forceinline__ u16 f2bf(float f) {
  union { float f; uint32_t u; } v; v.f = f;
  uint32_t r = v.u + 0x7FFFu + ((v.u >> 16) & 1u);
  return (u16)(r >> 16);
}
__device__ __forceinline__ float bf2f(u16 u) {
  union { uint32_t u; float f; } v; v.u = ((uint32_t)u) << 16; return v.f;
}
__device__ __forceinline__ float exp2a(float x) {
  float r; asm("v_exp_f32 %0, %1" : "=v"(r) : "v"(x)); return r;
}
__device__ __forceinline__ float rcpa(float x) {
  float r; asm("v_rcp_f32 %0, %1" : "=v"(r) : "v"(x)); return r;
}

typedef __attribute__((address_space(1))) const unsigned int ga_u32;
typedef __attribute__((address_space(3))) unsigned int ls_u32;
__device__ __forceinline__ void glds16(const u16* g, u16* l) {
  __builtin_amdgcn_global_load_lds((ga_u32*)g, (ls_u32*)l, 16, 0, 0);
}

// ---------------- fused prep: 4 weight transposes + LN1 in ONE node ----------------
__device__ __forceinline__ void tcast_body(const float* __restrict__ W, u16* __restrict__ Wt,
                                           int K, int N, int bx, int by, int tid,
                                           float (*tile)[33]) {
  int n0 = bx * 32, k0 = by * 32;
  int tx = tid & 31, ty = tid >> 5;
  #pragma unroll
  for (int r = 0; r < 32; r += 8)
    tile[r + ty][tx] = W[(size_t)(k0 + r + ty) * N + n0 + tx];
  __syncthreads();
  #pragma unroll
  for (int r = 0; r < 32; r += 8)
    Wt[(size_t)(n0 + r + ty) * K + k0 + tx] = f2bf(tile[tx][r + ty]);
}

__global__ __launch_bounds__(256) void prep_kernel(
    const float* __restrict__ x, const float* __restrict__ g, const float* __restrict__ b,
    const float* __restrict__ wqkv, const float* __restrict__ wproj,
    const float* __restrict__ wff1, const float* __restrict__ wff2,
    u16* __restrict__ ln_out, u16* __restrict__ wqkvT, u16* __restrict__ wprojT,
    u16* __restrict__ wff1T, u16* __restrict__ wff2T) {
  __shared__ float tile[32][33];
  int bid = blockIdx.x, tid = threadIdx.x;
  if (bid < 768) {            // wqkv: K=512, N=1536, nx=48
    tcast_body(wqkv, wqkvT, CMOD, CQKV, bid % 48, bid / 48, tid, tile);
  } else if (bid < 1024) {    // wproj: 512x512, nx=16
    int id = bid - 768; tcast_body(wproj, wprojT, CMOD, CMOD, id % 16, id / 16, tid, tile);
  } else if (bid < 2048) {    // wff1: K=512, N=2048, nx=64
    int id = bid - 1024; tcast_body(wff1, wff1T, CMOD, DFF, id % 64, id / 64, tid, tile);
  } else if (bid < 3072) {    // wff2: K=2048, N=512, nx=16
    int id = bid - 2048; tcast_body(wff2, wff2T, DFF, CMOD, id % 16, id / 16, tid, tile);
  } else {                    // LN1: 4 rows/block
    int row = (bid - 3072) * 4 + (tid >> 6);
    int lane = tid & 63;
    const float4* xr = (const float4*)(x + (size_t)row * CMOD);
    float4 a = xr[lane], c = xr[lane + 64];
    float s = a.x + a.y + a.z + a.w + c.x + c.y + c.z + c.w;
    float q = a.x*a.x + a.y*a.y + a.z*a.z + a.w*a.w
            + c.x*c.x + c.y*c.y + c.z*c.z + c.w*c.w;
    #pragma unroll
    for (int o = 32; o; o >>= 1) { s += __shfl_xor(s, o); q += __shfl_xor(q, o); }
    float mu = s * (1.0f / CMOD);
    float rstd = rsqrtf(q * (1.0f / CMOD) - mu * mu + 1e-5f);
    const float4* gr = (const float4*)g;
    const float4* br = (const float4*)b;
    float4 g0 = gr[lane], g1 = gr[lane + 64], b0 = br[lane], b1 = br[lane + 64];
    u16* orow = ln_out + (size_t)row * CMOD;
    int i0 = lane * 4, i1 = (lane + 64) * 4;
    orow[i0 + 0] = f2bf((a.x - mu) * rstd * g0.x + b0.x);
    orow[i0 + 1] = f2bf((a.y - mu) * rstd * g0.y + b0.y);
    orow[i0 + 2] = f2bf((a.z - mu) * rstd * g0.z + b0.z);
    orow[i0 + 3] = f2bf((a.w - mu) * rstd * g0.w + b0.w);
    orow[i1 + 0] = f2bf((c.x - mu) * rstd * g1.x + b1.x);
    orow[i1 + 1] = f2bf((c.y - mu) * rstd * g1.y + b1.y);
    orow[i1 + 2] = f2bf((c.z - mu) * rstd * g1.z + b1.z);
    orow[i1 + 3] = f2bf((c.w - mu) * rstd * g1.w + b1.w);
  }
}

// ---------------- layernorm (standalone, for LN2) ----------------
__global__ __launch_bounds__(256) void ln_kernel(const float* __restrict__ x,
                                                 const float* __restrict__ g,
                                                 const float* __restrict__ b,
                                                 u16* __restrict__ out) {
  int row = blockIdx.x * 4 + (threadIdx.x >> 6);
  int lane = threadIdx.x & 63;
  const float4* xr = (const float4*)(x + (size_t)row * CMOD);
  float4 a = xr[lane], c = xr[lane + 64];
  float s = a.x + a.y + a.z + a.w + c.x + c.y + c.z + c.w;
  float q = a.x*a.x + a.y*a.y + a.z*a.z + a.w*a.w
          + c.x*c.x + c.y*c.y + c.z*c.z + c.w*c.w;
  #pragma unroll
  for (int o = 32; o; o >>= 1) { s += __shfl_xor(s, o); q += __shfl_xor(q, o); }
  float mu = s * (1.0f / CMOD);
  float rstd = rsqrtf(q * (1.0f / CMOD) - mu * mu + 1e-5f);
  const float4* gr = (const float4*)g;
  const float4* br = (const float4*)b;
  float4 g0 = gr[lane], g1 = gr[lane + 64], b0 = br[lane], b1 = br[lane + 64];
  u16* orow = out + (size_t)row * CMOD;
  int i0 = lane * 4, i1 = (lane + 64) * 4;
  orow[i0 + 0] = f2bf((a.x - mu) * rstd * g0.x + b0.x);
  orow[i0 + 1] = f2bf((a.y - mu) * rstd * g0.y + b0.y);
  orow[i0 + 2] = f2bf((a.z - mu) * rstd * g0.z + b0.z);
  orow[i0 + 3] = f2bf((a.w - mu) * rstd * g0.w + b0.w);
  orow[i1 + 0] = f2bf((c.x - mu) * rstd * g1.x + b1.x);
  orow[i1 + 1] = f2bf((c.y - mu) * rstd * g1.y + b1.y);
  orow[i1 + 2] = f2bf((c.z - mu) * rstd * g1.z + b1.z);
  orow[i1 + 3] = f2bf((c.w - mu) * rstd * g1.w + b1.w);
}

// ---------------- MFMA GEMM (unchanged structure from R3) ----------------
template <int EPI, int TN>
__global__ __launch_bounds__(256) void gemm_kernel(
    const u16* __restrict__ A, const u16* __restrict__ Bt, int K,
    const float* __restrict__ resid, float* __restrict__ outf,
    u16* __restrict__ ob0, u16* __restrict__ ob1, u16* __restrict__ ob2) {
  constexpr int WNF = TN / 32;
  constexpr int NKB = TN / 64;
  __shared__ __align__(16) u16 As[2][128 * 32];
  __shared__ __align__(16) u16 Bs[2][TN * 32];
  int tid = threadIdx.x;
  int lane = tid & 63, wave = tid >> 6;
  int lane16 = lane & 15, quad = lane >> 4;
  int m0 = blockIdx.y * 128, n0 = blockIdx.x * TN;
  int wm = (wave >> 1) * 64, wn = (wave & 1) * (TN / 2);

  floatx4 acc[4][WNF];
  #pragma unroll
  for (int i = 0; i < 4; i++)
    #pragma unroll
    for (int j = 0; j < WNF; j++) acc[i][j] = (floatx4)(0.0f);

  const u16* agp[2]; u16* alp[2][2];
  const u16* bgp[NKB]; u16* blp[NKB][2];
  #pragma unroll
  for (int i = 0; i < 2; i++) {
    int s = i * 256 + tid;
    agp[i] = A + (size_t)(m0 + (s >> 2)) * K + (s & 3) * 8;
    alp[i][0] = &As[0][(i * 256 + wave * 64) * 8];
    alp[i][1] = &As[1][(i * 256 + wave * 64) * 8];
  }
  #pragma unroll
  for (int i = 0; i < NKB; i++) {
    int s = i * 256 + tid;
    bgp[i] = Bt + (size_t)(n0 + (s >> 2)) * K + (s & 3) * 8;
    blp[i][0] = &Bs[0][(i * 256 + wave * 64) * 8];
    blp[i][1] = &Bs[1][(i * 256 + wave * 64) * 8];
  }

  int nk = K >> 5;
  #pragma unroll
  for (int i = 0; i < 2; i++) glds16(agp[i], alp[i][0]);
  #pragma unroll
  for (int i = 0; i < NKB; i++) glds16(bgp[i], blp[i][0]);

  for (int kt = 0; kt < nk; kt++) {
    __syncthreads();
    int buf = kt & 1;
    if (kt + 1 < nk) {
      int k1 = (kt + 1) * 32;
      #pragma unroll
      for (int i = 0; i < 2; i++) glds16(agp[i] + k1, alp[i][buf ^ 1]);
      #pragma unroll
      for (int i = 0; i < NKB; i++) glds16(bgp[i] + k1, blp[i][buf ^ 1]);
    }
    short8 af[4], bf[WNF];
    #pragma unroll
    for (int i = 0; i < 4; i++)
      af[i] = *(const short8*)&As[buf][(wm + i * 16 + lane16) * 32 + quad * 8];
    #pragma unroll
    for (int j = 0; j < WNF; j++)
      bf[j] = *(const short8*)&Bs[buf][(wn + j * 16 + lane16) * 32 + quad * 8];
    #pragma unroll
    for (int i = 0; i < 4; i++)
      #pragma unroll
      for (int j = 0; j < WNF; j++)
        acc[i][j] = __builtin_amdgcn_mfma_f32_16x16x32_bf16(af[i], bf[j], acc[i][j], 0, 0, 0);
  }

  #pragma unroll
  for (int i = 0; i < 4; i++) {
    #pragma unroll
    for (int j = 0; j < WNF; j++) {
      #pragma unroll
      for (int r = 0; r < 4; r++) {
        int m = m0 + wm + i * 16 + quad * 4 + r;
        int n = n0 + wn + j * 16 + lane16;
        float v = acc[i][j][r];
        if (EPI == 0) {
          int bb = m >> 11, t = m & 2047;
          int nn = n & 511, which = n >> 9;
          int h = nn >> 7, d = nn & 127;
          size_t bh = (size_t)(bb * NH + h);
          if (which == 0)      ob0[bh * TSEQ * HD + (size_t)t * HD + d] = f2bf(v * 0.12751743f);
          else if (which == 1) ob1[bh * TSEQ * HD + (size_t)t * HD + d] = f2bf(v);
          else                 ob2[bh * HD * TSEQ + (size_t)d * TSEQ + t] = f2bf(v);
        } else if (EPI == 1) {
          size_t idx = (size_t)m * CMOD + n;
          outf[idx] = v + resid[idx];
        } else if (EPI == 2) {
          float ge = 0.5f * v * (1.0f + erff(v * 0.70710678118654752f));
          ob0[(size_t)m * DFF + n] = f2bf(ge);
        } else {
          size_t idx = (size_t)m * CMOD + n;
          outf[idx] = v + resid[idx];
        }
      }
    }
  }
}

// ---------------- flash attention v4: k-chunked (additive merge, no-max softmax) ----------------
// block = (bh, qt, chunk of <=16 k-tiles). Writes partial O (bf16) + partial l (f32).
__global__ __launch_bounds__(256) void attn_kernel(const u16* __restrict__ qb,
                                                   const u16* __restrict__ kb,
                                                   const u16* __restrict__ vtb,
                                                   u16* __restrict__ po,
                                                   float* __restrict__ pl) {
  __shared__ __align__(16) u16 Ks[2][32 * 128];
  __shared__ __align__(16) u16 Vs[2][128 * 32];
  __shared__ __align__(16) uint32_t Ps[4 * 16 * 20];
  int tid = threadIdx.x, wave = tid >> 6, lane = tid & 63;
  int lane16 = lane & 15, quad = lane >> 4;
  int bh = blockIdx.x;
  int cid = 79 - (int)blockIdx.y;  // heavy chunks dispatch first
  int qt, c;
  if (cid < 8)       { qt = cid;                  c = 0; }
  else if (cid < 24) { qt = 8 + ((cid - 8) >> 1); c = (cid - 8) & 1; }
  else if (cid < 48) { qt = 16 + (cid - 24) / 3;  c = (cid - 24) % 3; }
  else               { qt = 24 + ((cid - 48) >> 2); c = (cid - 48) & 3; }

  int q0w = qt * 64 + wave * 16;
  const u16* Q  = qb  + (size_t)bh * TSEQ * HD;
  const u16* Kg = kb  + (size_t)bh * TSEQ * HD;
  const u16* Vg = vtb + (size_t)bh * HD * TSEQ;

  short8 aq[4];
  {
    int qrow = q0w + lane16;
    #pragma unroll
    for (int cc = 0; cc < 4; cc++)
      aq[cc] = *(const short8*)&Q[(size_t)qrow * HD + cc * 32 + quad * 8];
  }

  const u16* kgp[2]; const u16* vgp[2];
  u16* klp[2][2]; u16* vlp[2][2];
  #pragma unroll
  for (int i = 0; i < 2; i++) {
    int s = wave * 128 + i * 64 + lane;
    int r = s >> 4, cp = s & 15, cc = cp ^ (r & 7);
    kgp[i] = Kg + (size_t)r * HD + cc * 8;
    int d = s >> 2, cv = (s & 3) ^ ((d >> 1) & 3);
    vgp[i] = Vg + (size_t)d * TSEQ + cv * 8;
    #pragma unroll
    for (int bfr = 0; bfr < 2; bfr++) {
      klp[i][bfr] = &Ks[bfr][(wave * 128 + i * 64) * 8];
      vlp[i][bfr] = &Vs[bfr][(wave * 128 + i * 64) * 8];
    }
  }

  int ktw   = (q0w >> 5) + 1;           // wave causal tile count (global)
  int ktblk = qt * 2 + 2;               // full tile count for this q-tile
  int kt0   = c * 16;
  int kend  = min(kt0 + 16, ktblk);     // block staging range [kt0, kend)

  floatx4 o[8];
  #pragma unroll
  for (int j = 0; j < 8; j++) o[j] = (floatx4)(0.0f);
  floatx4 ol = (floatx4)(0.0f);

  short8 ones;
  #pragma unroll
  for (int e = 0; e < 8; e++) ones[e] = (short)0x3F80;

  uint32_t* Pw = &Ps[wave * 320];
  int swl = lane16 & 7;
  int cvr = quad ^ ((lane16 >> 1) & 3);

  // prologue: stage tile kt0 into buffer (kt0 & 1)
  {
    int ko = kt0 * 32;
    #pragma unroll
    for (int i = 0; i < 2; i++) {
      glds16(kgp[i] + (size_t)ko * HD, klp[i][kt0 & 1]);
      glds16(vgp[i] + ko, vlp[i][kt0 & 1]);
    }
  }

  for (int kt = kt0; kt < kend; kt++) {
    __syncthreads();
    int buf = kt & 1;
    if (kt + 1 < kend) {
      int ko = (kt + 1) * 32;
      #pragma unroll
      for (int i = 0; i < 2; i++) {
        glds16(kgp[i] + (size_t)ko * HD, klp[i][buf ^ 1]);
        glds16(vgp[i] + ko, vlp[i][buf ^ 1]);
      }
    }
    if (kt >= ktw) continue;  // wave-uniform; barrier count aligned

    floatx4 st0 = (floatx4)(0.0f), st1 = (floatx4)(0.0f);
    #pragma unroll
    for (int cc = 0; cc < 4; cc++) {
      short8 kf0 = *(const short8*)&Ks[buf][(lane16 * 16 + ((cc * 4 + quad) ^ swl)) * 8];
      short8 kf1 = *(const short8*)&Ks[buf][((16 + lane16) * 16 + ((cc * 4 + quad) ^ swl)) * 8];
      st0 = __builtin_amdgcn_mfma_f32_16x16x32_bf16(aq[cc], kf0, st0, 0, 0, 0);
      st1 = __builtin_amdgcn_mfma_f32_16x16x32_bf16(aq[cc], kf1, st1, 0, 0, 0);
    }
    short8 vf[8];
    #pragma unroll
    for (int j = 0; j < 8; j++)
      vf[j] = *(const short8*)&Vs[buf][((j * 16 + lane16) * 4 + cvr) * 8];

    int kg0 = kt * 32 + lane16;
    #pragma unroll
    for (int r = 0; r < 4; r++) {
      int qr = q0w + quad * 4 + r;
      float p0 = exp2a(st0[r]);
      float p1 = exp2a(st1[r]);
      if (kg0 > qr) p0 = 0.0f;
      if (kg0 + 16 > qr) p1 = 0.0f;
      Pw[(quad * 4 + r) * 20 + lane16] =
          __builtin_amdgcn_perm(__float_as_uint(p1), __float_as_uint(p0), 0x07060302u);
    }
    asm volatile("s_waitcnt lgkmcnt(0)" ::: "memory");

    union { uint32_t u[4]; short8 s; } pf;
    {
      const uint32_t* prow = &Pw[lane16 * 20 + (quad & 1) * 8];
      uint32_t d0 = prow[0], d1 = prow[1], d2 = prow[2], d3 = prow[3];
      uint32_t d4 = prow[4], d5 = prow[5], d6 = prow[6], d7 = prow[7];
      uint32_t sel = (quad >> 1) ? 0x07060302u : 0x05040100u;
      pf.u[0] = __builtin_amdgcn_perm(d1, d0, sel);
      pf.u[1] = __builtin_amdgcn_perm(d3, d2, sel);
      pf.u[2] = __builtin_amdgcn_perm(d5, d4, sel);
      pf.u[3] = __builtin_amdgcn_perm(d7, d6, sel);
    }
    #pragma unroll
    for (int j = 0; j < 8; j++)
      o[j] = __builtin_amdgcn_mfma_f32_16x16x32_bf16(pf.s, vf[j], o[j], 0, 0, 0);
    ol = __builtin_amdgcn_mfma_f32_16x16x32_bf16(pf.s, ones, ol, 0, 0, 0);
  }

  // write partial slot (bh, qt, c): O bf16 [64][128], l f32 [64]
  int slot = (bh * 32 + qt) * 4 + c;
  u16* pob = po + (size_t)slot * 8192;
  #pragma unroll
  for (int r = 0; r < 4; r++) {
    int qr = wave * 16 + quad * 4 + r;
    #pragma unroll
    for (int j = 0; j < 8; j++)
      pob[qr * 128 + j * 16 + lane16] = f2bf(o[j][r]);
    if (lane16 == 0) pl[slot * 64 + qr] = ol[r];
  }
}

// ---------------- reduce: sum partials, normalize, cast to attn bf16 ----------------
__global__ __launch_bounds__(256) void reduce_kernel(const u16* __restrict__ po,
                                                     const float* __restrict__ pl,
                                                     u16* __restrict__ attn) {
  int bh = blockIdx.x >> 5, qt = blockIdx.x & 31;
  int tid = threadIdx.x;
  int nch = (2 * qt + 17) >> 4;
  int qrow = tid >> 2;
  int d0 = (tid & 3) * 32;
  float acc[32];
  #pragma unroll
  for (int i = 0; i < 32; i++) acc[i] = 0.0f;
  float l = 0.0f;
  int slot0 = (bh * 32 + qt) * 4;
  for (int c = 0; c < nch; c++) {
    int slot = slot0 + c;
    l += pl[slot * 64 + qrow];
    const short8* p = (const short8*)(po + (size_t)slot * 8192 + qrow * 128 + d0);
    #pragma unroll
    for (int v = 0; v < 4; v++) {
      short8 pk = p[v];
      #pragma unroll
      for (int e = 0; e < 8; e++) acc[v * 8 + e] += bf2f((u16)pk[e]);
    }
  }
  float inv = rcpa(l);
  int b = bh >> 2, h = bh & 3, t = qt * 64 + qrow;
  u16* orow = attn + ((size_t)(b * TSEQ + t)) * CMOD + h * HD + d0;
  #pragma unroll
  for (int v = 0; v < 4; v++) {
    short8 ov;
    #pragma unroll
    for (int e = 0; e < 8; e++) ov[e] = (short)f2bf(acc[v * 8 + e] * inv);
    *(short8*)(orow + v * 8) = ov;
  }
}

extern "C" void kernel_launch(void* const* d_in, const int* in_sizes, int n_in,
                              void* d_out, int out_size, void* d_ws, size_t ws_size,
                              hipStream_t stream) {
  const float* x     = (const float*)d_in[0];
  const float* ln1g  = (const float*)d_in[1];
  const float* ln1b  = (const float*)d_in[2];
  const float* wqkv  = (const float*)d_in[3];
  const float* wproj = (const float*)d_in[4];
  const float* ln2g  = (const float*)d_in[5];
  const float* ln2b  = (const float*)d_in[6];
  const float* wff1  = (const float*)d_in[7];
  const float* wff2  = (const float*)d_in[8];
  float* out = (float*)d_out;
  char* ws = (char*)d_ws;

  u16* wt_qkv  = (u16*)(ws);             // 1536x512 bf16
  u16* wt_proj = (u16*)(ws + 1572864);
  u16* wt_ff1  = (u16*)(ws + 2097152);
  u16* wt_ff2  = (u16*)(ws + 4194304);
  u16* ln_buf  = (u16*)(ws + 6291456);
  u16* q_buf   = (u16*)(ws + 14680064);
  u16* k_buf   = (u16*)(ws + 23068672);
  u16* vt_buf  = (u16*)(ws + 31457280);
  u16* attn    = (u16*)(ws + 39845888);
  float* x2    = (float*)(ws + 48234496); // born AFTER partials die
  u16* h1      = (u16*)(ws + 65011712);
  // attention partials overlap x2/h1 region (dead by proj time)
  u16* po      = (u16*)(ws + 48234496);   // 2048 slots x 64x128 bf16 = 33.5 MB
  float* pl    = (float*)(ws + 81788928); // 2048 x 64 f32

  dim3 blk(256);
  prep_kernel<<<dim3(5120), blk, 0, stream>>>(x, ln1g, ln1b, wqkv, wproj, wff1, wff2,
                                              ln_buf, wt_qkv, wt_proj, wt_ff1, wt_ff2);

  gemm_kernel<0, 128><<<dim3(CQKV / 128, BT / 128), blk, 0, stream>>>(
      ln_buf, wt_qkv, CMOD, nullptr, nullptr, q_buf, k_buf, vt_buf);

  attn_kernel<<<dim3(NBAT * NH, 80), blk, 0, stream>>>(q_buf, k_buf, vt_buf, po, pl);

  reduce_kernel<<<dim3(512), blk, 0, stream>>>(po, pl, attn);

  gemm_kernel<1, 64><<<dim3(CMOD / 64, BT / 128), blk, 0, stream>>>(
      attn, wt_proj, CMOD, x, x2, nullptr, nullptr, nullptr);

  ln_kernel<<<dim3(BT / 4), blk, 0, stream>>>(x2, ln2g, ln2b, ln_buf);

  gemm_kernel<2, 128><<<dim3(DFF / 128, BT / 128), blk, 0, stream>>>(
      ln_buf, wt_ff1, CMOD, nullptr, nullptr, h1, nullptr, nullptr);

  gemm_kernel<3, 64><<<dim3(CMOD / 64, BT / 128), blk, 0, stream>>>(
      h1, wt_ff2, DFF, x2, out, nullptr, nullptr, nullptr);
}

// Round 7
// 269.044 us; speedup vs baseline: 1.3532x; 1.0284x over previous
//
#include <hip/hip_runtime.h>
#include <cstdint>

typedef unsigned short u16;
typedef __attribute__((ext_vector_type(8))) short short8;
typedef __attribute__((ext_vector_type(4))) float floatx4;

#define BT    8192
#define TSEQ  2048
#define NBAT  4
#define CMOD  512
#define NH    4
#define HD    128
#define DFF   2048
#define CQKV  1536

__device__ __forceinline__ u16 f2bf(float f) {
  union { float f; uint32_t u; } v; v.f = f;
  uint32_t r = v.u + 0x7FFFu + ((v.u >> 16) & 1u);
  return (u16)(r >> 16);
}
__device__ __forceinline__ float bf2f(u16 u) {
  union { uint32_t u; float f; } v; v.u = ((uint32_t)u) << 16; return v.f;
}
__device__ __forceinline__ float exp2a(float x) {
  float r; asm("v_exp_f32 %0, %1" : "=v"(r) : "v"(x)); return r;
}
__device__ __forceinline__ float rcpa(float x) {
  float r; asm("v_rcp_f32 %0, %1" : "=v"(r) : "v"(x)); return r;
}

typedef __attribute__((address_space(1))) const unsigned int ga_u32;
typedef __attribute__((address_space(3))) unsigned int ls_u32;
__device__ __forceinline__ void glds16(const u16* g, u16* l) {
  __builtin_amdgcn_global_load_lds((ga_u32*)g, (ls_u32*)l, 16, 0, 0);
}

// ---------------- fused prep: 4 weight transposes + LN1 (R4-proven) ----------------
__device__ __forceinline__ void tcast_body(const float* __restrict__ W, u16* __restrict__ Wt,
                                           int K, int N, int bx, int by, int tid,
                                           float (*tile)[33]) {
  int n0 = bx * 32, k0 = by * 32;
  int tx = tid & 31, ty = tid >> 5;
  #pragma unroll
  for (int r = 0; r < 32; r += 8)
    tile[r + ty][tx] = W[(size_t)(k0 + r + ty) * N + n0 + tx];
  __syncthreads();
  #pragma unroll
  for (int r = 0; r < 32; r += 8)
    Wt[(size_t)(n0 + r + ty) * K + k0 + tx] = f2bf(tile[tx][r + ty]);
}

__global__ __launch_bounds__(256) void prep_kernel(
    const float* __restrict__ x, const float* __restrict__ g, const float* __restrict__ b,
    const float* __restrict__ wqkv, const float* __restrict__ wproj,
    const float* __restrict__ wff1, const float* __restrict__ wff2,
    u16* __restrict__ ln_out, u16* __restrict__ wqkvT, u16* __restrict__ wprojT,
    u16* __restrict__ wff1T, u16* __restrict__ wff2T) {
  __shared__ float tile[32][33];
  int bid = blockIdx.x, tid = threadIdx.x;
  if (bid < 768) {
    tcast_body(wqkv, wqkvT, CMOD, CQKV, bid % 48, bid / 48, tid, tile);
  } else if (bid < 1024) {
    int id = bid - 768; tcast_body(wproj, wprojT, CMOD, CMOD, id % 16, id / 16, tid, tile);
  } else if (bid < 2048) {
    int id = bid - 1024; tcast_body(wff1, wff1T, CMOD, DFF, id % 64, id / 64, tid, tile);
  } else if (bid < 3072) {
    int id = bid - 2048; tcast_body(wff2, wff2T, DFF, CMOD, id % 16, id / 16, tid, tile);
  } else {
    int row = (bid - 3072) * 4 + (tid >> 6);
    int lane = tid & 63;
    const float4* xr = (const float4*)(x + (size_t)row * CMOD);
    float4 a = xr[lane], c = xr[lane + 64];
    float s = a.x + a.y + a.z + a.w + c.x + c.y + c.z + c.w;
    float q = a.x*a.x + a.y*a.y + a.z*a.z + a.w*a.w
            + c.x*c.x + c.y*c.y + c.z*c.z + c.w*c.w;
    #pragma unroll
    for (int o = 32; o; o >>= 1) { s += __shfl_xor(s, o); q += __shfl_xor(q, o); }
    float mu = s * (1.0f / CMOD);
    float rstd = rsqrtf(q * (1.0f / CMOD) - mu * mu + 1e-5f);
    const float4* gr = (const float4*)g;
    const float4* br = (const float4*)b;
    float4 g0 = gr[lane], g1 = gr[lane + 64], b0 = br[lane], b1 = br[lane + 64];
    u16* orow = ln_out + (size_t)row * CMOD;
    int i0 = lane * 4, i1 = (lane + 64) * 4;
    orow[i0 + 0] = f2bf((a.x - mu) * rstd * g0.x + b0.x);
    orow[i0 + 1] = f2bf((a.y - mu) * rstd * g0.y + b0.y);
    orow[i0 + 2] = f2bf((a.z - mu) * rstd * g0.z + b0.z);
    orow[i0 + 3] = f2bf((a.w - mu) * rstd * g0.w + b0.w);
    orow[i1 + 0] = f2bf((c.x - mu) * rstd * g1.x + b1.x);
    orow[i1 + 1] = f2bf((c.y - mu) * rstd * g1.y + b1.y);
    orow[i1 + 2] = f2bf((c.z - mu) * rstd * g1.z + b1.z);
    orow[i1 + 3] = f2bf((c.w - mu) * rstd * g1.w + b1.w);
  }
}

// ---------------- layernorm (standalone, for LN2; R4-proven) ----------------
__global__ __launch_bounds__(256) void ln_kernel(const float* __restrict__ x,
                                                 const float* __restrict__ g,
                                                 const float* __restrict__ b,
                                                 u16* __restrict__ out) {
  int row = blockIdx.x * 4 + (threadIdx.x >> 6);
  int lane = threadIdx.x & 63;
  const float4* xr = (const float4*)(x + (size_t)row * CMOD);
  float4 a = xr[lane], c = xr[lane + 64];
  float s = a.x + a.y + a.z + a.w + c.x + c.y + c.z + c.w;
  float q = a.x*a.x + a.y*a.y + a.z*a.z + a.w*a.w
          + c.x*c.x + c.y*c.y + c.z*c.z + c.w*c.w;
  #pragma unroll
  for (int o = 32; o; o >>= 1) { s += __shfl_xor(s, o); q += __shfl_xor(q, o); }
  float mu = s * (1.0f / CMOD);
  float rstd = rsqrtf(q * (1.0f / CMOD) - mu * mu + 1e-5f);
  const float4* gr = (const float4*)g;
  const float4* br = (const float4*)b;
  float4 g0 = gr[lane], g1 = gr[lane + 64], b0 = br[lane], b1 = br[lane + 64];
  u16* orow = out + (size_t)row * CMOD;
  int i0 = lane * 4, i1 = (lane + 64) * 4;
  orow[i0 + 0] = f2bf((a.x - mu) * rstd * g0.x + b0.x);
  orow[i0 + 1] = f2bf((a.y - mu) * rstd * g0.y + b0.y);
  orow[i0 + 2] = f2bf((a.z - mu) * rstd * g0.z + b0.z);
  orow[i0 + 3] = f2bf((a.w - mu) * rstd * g0.w + b0.w);
  orow[i1 + 0] = f2bf((c.x - mu) * rstd * g1.x + b1.x);
  orow[i1 + 1] = f2bf((c.y - mu) * rstd * g1.y + b1.y);
  orow[i1 + 2] = f2bf((c.z - mu) * rstd * g1.z + b1.z);
  orow[i1 + 3] = f2bf((c.w - mu) * rstd * g1.w + b1.w);
}

// ---------------- MFMA GEMM: THE ONLY CHANGE vs R4 ----------------
// af-held / bfj-streamed inner loop + __launch_bounds__(256,4).
// Math is per-acc-element identical to R4; bounds only constrain the allocator.
template <int EPI, int TN>
__global__ __launch_bounds__(256, 4) void gemm_kernel(
    const u16* __restrict__ A, const u16* __restrict__ Bt, int K,
    const float* __restrict__ resid, float* __restrict__ outf,
    u16* __restrict__ ob0, u16* __restrict__ ob1, u16* __restrict__ ob2) {
  constexpr int WNF = TN / 32;
  constexpr int NKB = TN / 64;
  __shared__ __align__(16) u16 As[2][128 * 32];
  __shared__ __align__(16) u16 Bs[2][TN * 32];
  int tid = threadIdx.x;
  int lane = tid & 63, wave = tid >> 6;
  int lane16 = lane & 15, quad = lane >> 4;
  int m0 = blockIdx.y * 128, n0 = blockIdx.x * TN;
  int wm = (wave >> 1) * 64, wn = (wave & 1) * (TN / 2);

  floatx4 acc[4][WNF];
  #pragma unroll
  for (int i = 0; i < 4; i++)
    #pragma unroll
    for (int j = 0; j < WNF; j++) acc[i][j] = (floatx4)(0.0f);

  const u16* agp[2]; u16* alp[2][2];
  const u16* bgp[NKB]; u16* blp[NKB][2];
  #pragma unroll
  for (int i = 0; i < 2; i++) {
    int s = i * 256 + tid;
    agp[i] = A + (size_t)(m0 + (s >> 2)) * K + (s & 3) * 8;
    alp[i][0] = &As[0][(i * 256 + wave * 64) * 8];
    alp[i][1] = &As[1][(i * 256 + wave * 64) * 8];
  }
  #pragma unroll
  for (int i = 0; i < NKB; i++) {
    int s = i * 256 + tid;
    bgp[i] = Bt + (size_t)(n0 + (s >> 2)) * K + (s & 3) * 8;
    blp[i][0] = &Bs[0][(i * 256 + wave * 64) * 8];
    blp[i][1] = &Bs[1][(i * 256 + wave * 64) * 8];
  }

  int nk = K >> 5;
  #pragma unroll
  for (int i = 0; i < 2; i++) glds16(agp[i], alp[i][0]);
  #pragma unroll
  for (int i = 0; i < NKB; i++) glds16(bgp[i], blp[i][0]);

  for (int kt = 0; kt < nk; kt++) {
    __syncthreads();
    int buf = kt & 1;
    if (kt + 1 < nk) {
      int k1 = (kt + 1) * 32;
      #pragma unroll
      for (int i = 0; i < 2; i++) glds16(agp[i] + k1, alp[i][buf ^ 1]);
      #pragma unroll
      for (int i = 0; i < NKB; i++) glds16(bgp[i] + k1, blp[i][buf ^ 1]);
    }
    short8 af[4];
    #pragma unroll
    for (int i = 0; i < 4; i++)
      af[i] = *(const short8*)&As[buf][(wm + i * 16 + lane16) * 32 + quad * 8];
    #pragma unroll
    for (int j = 0; j < WNF; j++) {
      short8 bfj = *(const short8*)&Bs[buf][(wn + j * 16 + lane16) * 32 + quad * 8];
      #pragma unroll
      for (int i = 0; i < 4; i++)
        acc[i][j] = __builtin_amdgcn_mfma_f32_16x16x32_bf16(af[i], bfj, acc[i][j], 0, 0, 0);
    }
  }

  #pragma unroll
  for (int i = 0; i < 4; i++) {
    #pragma unroll
    for (int j = 0; j < WNF; j++) {
      #pragma unroll
      for (int r = 0; r < 4; r++) {
        int m = m0 + wm + i * 16 + quad * 4 + r;
        int n = n0 + wn + j * 16 + lane16;
        float v = acc[i][j][r];
        if (EPI == 0) {
          int bb = m >> 11, t = m & 2047;
          int nn = n & 511, which = n >> 9;
          int h = nn >> 7, d = nn & 127;
          size_t bh = (size_t)(bb * NH + h);
          if (which == 0)      ob0[bh * TSEQ * HD + (size_t)t * HD + d] = f2bf(v * 0.12751743f);
          else if (which == 1) ob1[bh * TSEQ * HD + (size_t)t * HD + d] = f2bf(v);
          else                 ob2[bh * HD * TSEQ + (size_t)d * TSEQ + t] = f2bf(v);
        } else if (EPI == 1) {
          size_t idx = (size_t)m * CMOD + n;
          outf[idx] = v + resid[idx];
        } else if (EPI == 2) {
          float ge = 0.5f * v * (1.0f + erff(v * 0.70710678118654752f));
          ob0[(size_t)m * DFF + n] = f2bf(ge);
        } else {
          size_t idx = (size_t)m * CMOD + n;
          outf[idx] = v + resid[idx];
        }
      }
    }
  }
}

// ---------------- flash attention: VERBATIM R4 (passed) ----------------
// k-chunked, double-buffered K/V, partials for all blocks, separate reduce.
__global__ __launch_bounds__(256) void attn_kernel(const u16* __restrict__ qb,
                                                   const u16* __restrict__ kb,
                                                   const u16* __restrict__ vtb,
                                                   u16* __restrict__ po,
                                                   float* __restrict__ pl) {
  __shared__ __align__(16) u16 Ks[2][32 * 128];
  __shared__ __align__(16) u16 Vs[2][128 * 32];
  __shared__ __align__(16) uint32_t Ps[4 * 16 * 20];
  int tid = threadIdx.x, wave = tid >> 6, lane = tid & 63;
  int lane16 = lane & 15, quad = lane >> 4;
  int bh = blockIdx.x;
  int cid = 79 - (int)blockIdx.y;  // heavy chunks dispatch first
  int qt, c;
  if (cid < 8)       { qt = cid;                    c = 0; }
  else if (cid < 24) { qt = 8 + ((cid - 8) >> 1);   c = (cid - 8) & 1; }
  else if (cid < 48) { qt = 16 + (cid - 24) / 3;    c = (cid - 24) % 3; }
  else               { qt = 24 + ((cid - 48) >> 2); c = (cid - 48) & 3; }

  int q0w = qt * 64 + wave * 16;
  const u16* Q  = qb  + (size_t)bh * TSEQ * HD;
  const u16* Kg = kb  + (size_t)bh * TSEQ * HD;
  const u16* Vg = vtb + (size_t)bh * HD * TSEQ;

  short8 aq[4];
  {
    int qrow = q0w + lane16;
    #pragma unroll
    for (int cc = 0; cc < 4; cc++)
      aq[cc] = *(const short8*)&Q[(size_t)qrow * HD + cc * 32 + quad * 8];
  }

  const u16* kgp[2]; const u16* vgp[2];
  u16* klp[2][2]; u16* vlp[2][2];
  #pragma unroll
  for (int i = 0; i < 2; i++) {
    int s = wave * 128 + i * 64 + lane;
    int r = s >> 4, cp = s & 15, cc = cp ^ (r & 7);
    kgp[i] = Kg + (size_t)r * HD + cc * 8;
    int d = s >> 2, cv = (s & 3) ^ ((d >> 1) & 3);
    vgp[i] = Vg + (size_t)d * TSEQ + cv * 8;
    #pragma unroll
    for (int bfr = 0; bfr < 2; bfr++) {
      klp[i][bfr] = &Ks[bfr][(wave * 128 + i * 64) * 8];
      vlp[i][bfr] = &Vs[bfr][(wave * 128 + i * 64) * 8];
    }
  }

  int ktw   = (q0w >> 5) + 1;
  int ktblk = qt * 2 + 2;
  int kt0   = c * 16;
  int kend  = min(kt0 + 16, ktblk);

  floatx4 o[8];
  #pragma unroll
  for (int j = 0; j < 8; j++) o[j] = (floatx4)(0.0f);
  floatx4 ol = (floatx4)(0.0f);

  short8 ones;
  #pragma unroll
  for (int e = 0; e < 8; e++) ones[e] = (short)0x3F80;

  uint32_t* Pw = &Ps[wave * 320];
  int swl = lane16 & 7;
  int cvr = quad ^ ((lane16 >> 1) & 3);

  {
    int ko = kt0 * 32;
    #pragma unroll
    for (int i = 0; i < 2; i++) {
      glds16(kgp[i] + (size_t)ko * HD, klp[i][kt0 & 1]);
      glds16(vgp[i] + ko, vlp[i][kt0 & 1]);
    }
  }

  for (int kt = kt0; kt < kend; kt++) {
    __syncthreads();
    int buf = kt & 1;
    if (kt + 1 < kend) {
      int ko = (kt + 1) * 32;
      #pragma unroll
      for (int i = 0; i < 2; i++) {
        glds16(kgp[i] + (size_t)ko * HD, klp[i][buf ^ 1]);
        glds16(vgp[i] + ko, vlp[i][buf ^ 1]);
      }
    }
    if (kt >= ktw) continue;

    floatx4 st0 = (floatx4)(0.0f), st1 = (floatx4)(0.0f);
    #pragma unroll
    for (int cc = 0; cc < 4; cc++) {
      short8 kf0 = *(const short8*)&Ks[buf][(lane16 * 16 + ((cc * 4 + quad) ^ swl)) * 8];
      short8 kf1 = *(const short8*)&Ks[buf][((16 + lane16) * 16 + ((cc * 4 + quad) ^ swl)) * 8];
      st0 = __builtin_amdgcn_mfma_f32_16x16x32_bf16(aq[cc], kf0, st0, 0, 0, 0);
      st1 = __builtin_amdgcn_mfma_f32_16x16x32_bf16(aq[cc], kf1, st1, 0, 0, 0);
    }
    short8 vf[8];
    #pragma unroll
    for (int j = 0; j < 8; j++)
      vf[j] = *(const short8*)&Vs[buf][((j * 16 + lane16) * 4 + cvr) * 8];

    int kg0 = kt * 32 + lane16;
    #pragma unroll
    for (int r = 0; r < 4; r++) {
      int qr = q0w + quad * 4 + r;
      float p0 = exp2a(st0[r]);
      float p1 = exp2a(st1[r]);
      if (kg0 > qr) p0 = 0.0f;
      if (kg0 + 16 > qr) p1 = 0.0f;
      Pw[(quad * 4 + r) * 20 + lane16] =
          __builtin_amdgcn_perm(__float_as_uint(p1), __float_as_uint(p0), 0x07060302u);
    }
    asm volatile("s_waitcnt lgkmcnt(0)" ::: "memory");

    union { uint32_t u[4]; short8 s; } pf;
    {
      const uint32_t* prow = &Pw[lane16 * 20 + (quad & 1) * 8];
      uint32_t d0 = prow[0], d1 = prow[1], d2 = prow[2], d3 = prow[3];
      uint32_t d4 = prow[4], d5 = prow[5], d6 = prow[6], d7 = prow[7];
      uint32_t sel = (quad >> 1) ? 0x07060302u : 0x05040100u;
      pf.u[0] = __builtin_amdgcn_perm(d1, d0, sel);
      pf.u[1] = __builtin_amdgcn_perm(d3, d2, sel);
      pf.u[2] = __builtin_amdgcn_perm(d5, d4, sel);
      pf.u[3] = __builtin_amdgcn_perm(d7, d6, sel);
    }
    #pragma unroll
    for (int j = 0; j < 8; j++)
      o[j] = __builtin_amdgcn_mfma_f32_16x16x32_bf16(pf.s, vf[j], o[j], 0, 0, 0);
    ol = __builtin_amdgcn_mfma_f32_16x16x32_bf16(pf.s, ones, ol, 0, 0, 0);
  }

  int slot = (bh * 32 + qt) * 4 + c;
  u16* pob = po + (size_t)slot * 8192;
  #pragma unroll
  for (int r = 0; r < 4; r++) {
    int qr = wave * 16 + quad * 4 + r;
    #pragma unroll
    for (int j = 0; j < 8; j++)
      pob[qr * 128 + j * 16 + lane16] = f2bf(o[j][r]);
    if (lane16 == 0) pl[slot * 64 + qr] = ol[r];
  }
}

// ---------------- reduce: VERBATIM R4 (passed), grid 512 covers all qt ----------------
__global__ __launch_bounds__(256) void reduce_kernel(const u16* __restrict__ po,
                                                     const float* __restrict__ pl,
                                                     u16* __restrict__ attn) {
  int bh = blockIdx.x >> 5, qt = blockIdx.x & 31;
  int tid = threadIdx.x;
  int nch = (2 * qt + 17) >> 4;
  int qrow = tid >> 2;
  int d0 = (tid & 3) * 32;
  float acc[32];
  #pragma unroll
  for (int i = 0; i < 32; i++) acc[i] = 0.0f;
  float l = 0.0f;
  int slot0 = (bh * 32 + qt) * 4;
  for (int c = 0; c < nch; c++) {
    int slot = slot0 + c;
    l += pl[slot * 64 + qrow];
    const short8* p = (const short8*)(po + (size_t)slot * 8192 + qrow * 128 + d0);
    #pragma unroll
    for (int v = 0; v < 4; v++) {
      short8 pk = p[v];
      #pragma unroll
      for (int e = 0; e < 8; e++) acc[v * 8 + e] += bf2f((u16)pk[e]);
    }
  }
  float inv = rcpa(l);
  int b = bh >> 2, h = bh & 3, t = qt * 64 + qrow;
  u16* orow = attn + ((size_t)(b * TSEQ + t)) * CMOD + h * HD + d0;
  #pragma unroll
  for (int v = 0; v < 4; v++) {
    short8 ov;
    #pragma unroll
    for (int e = 0; e < 8; e++) ov[e] = (short)f2bf(acc[v * 8 + e] * inv);
    *(short8*)(orow + v * 8) = ov;
  }
}

extern "C" void kernel_launch(void* const* d_in, const int* in_sizes, int n_in,
                              void* d_out, int out_size, void* d_ws, size_t ws_size,
                              hipStream_t stream) {
  const float* x     = (const float*)d_in[0];
  const float* ln1g  = (const float*)d_in[1];
  const float* ln1b  = (const float*)d_in[2];
  const float* wqkv  = (const float*)d_in[3];
  const float* wproj = (const float*)d_in[4];
  const float* ln2g  = (const float*)d_in[5];
  const float* ln2b  = (const float*)d_in[6];
  const float* wff1  = (const float*)d_in[7];
  const float* wff2  = (const float*)d_in[8];
  float* out = (float*)d_out;
  char* ws = (char*)d_ws;

  u16* wt_qkv  = (u16*)(ws);
  u16* wt_proj = (u16*)(ws + 1572864);
  u16* wt_ff1  = (u16*)(ws + 2097152);
  u16* wt_ff2  = (u16*)(ws + 4194304);
  u16* ln_buf  = (u16*)(ws + 6291456);
  u16* q_buf   = (u16*)(ws + 14680064);
  u16* k_buf   = (u16*)(ws + 23068672);
  u16* vt_buf  = (u16*)(ws + 31457280);
  u16* attn    = (u16*)(ws + 39845888);
  float* x2    = (float*)(ws + 48234496);
  u16* h1      = (u16*)(ws + 65011712);
  u16* po      = (u16*)(ws + 48234496);
  float* pl    = (float*)(ws + 81788928);

  dim3 blk(256);
  prep_kernel<<<dim3(5120), blk, 0, stream>>>(x, ln1g, ln1b, wqkv, wproj, wff1, wff2,
                                              ln_buf, wt_qkv, wt_proj, wt_ff1, wt_ff2);

  gemm_kernel<0, 128><<<dim3(CQKV / 128, BT / 128), blk, 0, stream>>>(
      ln_buf, wt_qkv, CMOD, nullptr, nullptr, q_buf, k_buf, vt_buf);

  attn_kernel<<<dim3(NBAT * NH, 80), blk, 0, stream>>>(q_buf, k_buf, vt_buf, po, pl);

  reduce_kernel<<<dim3(512), blk, 0, stream>>>(po, pl, attn);

  gemm_kernel<1, 64><<<dim3(CMOD / 64, BT / 128), blk, 0, stream>>>(
      attn, wt_proj, CMOD, x, x2, nullptr, nullptr, nullptr);

  ln_kernel<<<dim3(BT / 4), blk, 0, stream>>>(x2, ln2g, ln2b, ln_buf);

  gemm_kernel<2, 128><<<dim3(DFF / 128, BT / 128), blk, 0, stream>>>(
      ln_buf, wt_ff1, CMOD, nullptr, nullptr, h1, nullptr, nullptr);

  gemm_kernel<3, 64><<<dim3(CMOD / 64, BT / 128), blk, 0, stream>>>(
      h1, wt_ff2, DFF, x2, out, nullptr, nullptr, nullptr);
}